// Round 4
// baseline (512.414 us; speedup 1.0000x reference)
//
#include <hip/hip_runtime.h>

#define N_NODES 100000
#define N_EDGES 1600000
#define IN_CH 64
#define HID_CH 128

// Kernel 1: one 64-lane wave per edge.
// lane c: atomicAdd(agg[dst*64+c], h[src*64+c]); lane 0: atomicAdd(deg[dst], 1)
__global__ __launch_bounds__(256) void sage_scatter(
    const int* __restrict__ ei,     // [2, N_EDGES]: row0 = dst, row1 = src
    const float* __restrict__ h,    // [N_NODES, IN_CH]
    float* __restrict__ agg,        // [N_NODES, IN_CH] (zeroed)
    float* __restrict__ deg)        // [N_NODES] (zeroed)
{
    const int gtid = blockIdx.x * blockDim.x + threadIdx.x;
    const int edge = gtid >> 6;
    const int lane = threadIdx.x & 63;
    if (edge >= N_EDGES) return;
    const int dst = ei[edge];
    const int src = ei[N_EDGES + edge];
    const float v = h[(size_t)src * IN_CH + lane];
    atomicAdd(&agg[(size_t)dst * IN_CH + lane], v);
    if (lane == 0) atomicAdd(&deg[dst], 1.0f);
}

// Kernel 2: 128 threads/block, thread t owns output channel t.
// Weight columns cached in registers (64+64 floats, static unroll).
// Grid-stride over nodes; per-node mean/h broadcast via LDS.
__global__ __launch_bounds__(128) void sage_node(
    const float* __restrict__ h,     // [N_NODES, IN_CH]
    const float* __restrict__ agg,   // [N_NODES, IN_CH]
    const float* __restrict__ deg,   // [N_NODES]
    const float* __restrict__ Wl,    // [IN_CH, HID_CH]
    const float* __restrict__ bias,  // [HID_CH]
    const float* __restrict__ Wr,    // [IN_CH, HID_CH]
    float* __restrict__ out)         // [N_NODES, HID_CH]
{
    const int t = threadIdx.x;  // 0..127

    float wl[IN_CH], wr[IN_CH];
#pragma unroll
    for (int k = 0; k < IN_CH; ++k) {
        wl[k] = Wl[k * HID_CH + t];
        wr[k] = Wr[k * HID_CH + t];
    }
    const float b = bias[t];

    __shared__ float s_mean[IN_CH];
    __shared__ float s_h[IN_CH];

    for (int n = blockIdx.x; n < N_NODES; n += gridDim.x) {
        __syncthreads();
        if (t < IN_CH) {
            const float d = deg[n];
            const float inv = 1.0f / fmaxf(d, 1.0f);
            s_mean[t] = agg[(size_t)n * IN_CH + t] * inv;
            s_h[t] = h[(size_t)n * IN_CH + t];
        }
        __syncthreads();
        float acc = b;
#pragma unroll
        for (int k = 0; k < IN_CH; ++k) {
            acc = fmaf(s_mean[k], wl[k], acc);
            acc = fmaf(s_h[k], wr[k], acc);
        }
        out[(size_t)n * HID_CH + t] = acc;
    }
}

extern "C" void kernel_launch(void* const* d_in, const int* in_sizes, int n_in,
                              void* d_out, int out_size, void* d_ws, size_t ws_size,
                              hipStream_t stream) {
    // inputs: 0=x (unused), 1=edge_index, 2=emb_weight, 3=lin_l_w, 4=lin_l_b, 5=lin_r_w
    const int* ei = (const int*)d_in[1];
    const float* h = (const float*)d_in[2];
    const float* Wl = (const float*)d_in[3];
    const float* b = (const float*)d_in[4];
    const float* Wr = (const float*)d_in[5];
    float* out = (float*)d_out;

    float* agg = (float*)d_ws;                          // N_NODES*IN_CH floats
    float* deg = agg + (size_t)N_NODES * IN_CH;         // N_NODES floats

    const size_t zero_bytes = ((size_t)N_NODES * IN_CH + N_NODES) * sizeof(float);
    hipMemsetAsync(d_ws, 0, zero_bytes, stream);

    {
        const long long total = (long long)N_EDGES * 64;
        const int block = 256;
        const int grid = (int)((total + block - 1) / block);
        sage_scatter<<<grid, block, 0, stream>>>(ei, h, agg, deg);
    }
    {
        const int block = 128;
        const int grid = 4096;  // grid-stride over nodes; amortizes weight reg-load
        sage_node<<<grid, block, 0, stream>>>(h, agg, deg, Wl, b, Wr, out);
    }
}

// Round 5
// 436.490 us; speedup vs baseline: 1.1739x; 1.1739x over previous
//
#include <hip/hip_runtime.h>

#define N_NODES 100000
#define N_EDGES 1600000
#define IN_CH 64
#define HID_CH 128

#define SCAN_ELEMS 1024                                   // elems per scan block
#define NBLK_SCAN ((N_NODES + SCAN_ELEMS - 1) / SCAN_ELEMS)  // 98

// ---------------- CSR build ----------------

__global__ __launch_bounds__(256) void sage_hist(
    const int* __restrict__ ei, int* __restrict__ cnt)
{
    const int e = blockIdx.x * blockDim.x + threadIdx.x;
    if (e >= N_EDGES) return;
    atomicAdd(&cnt[ei[e]], 1);
}

// Per-block exclusive scan: block b covers cnt[b*1024 .. b*1024+1023].
// Writes local exclusive prefix to offs[], block total to parts[b].
__global__ __launch_bounds__(256) void sage_scan_blocks(
    const int* __restrict__ cnt, int* __restrict__ offs, int* __restrict__ parts)
{
    __shared__ int s[256];
    const int t = threadIdx.x;
    const int base = blockIdx.x * SCAN_ELEMS + t * 4;
    int v0 = (base + 0 < N_NODES) ? cnt[base + 0] : 0;
    int v1 = (base + 1 < N_NODES) ? cnt[base + 1] : 0;
    int v2 = (base + 2 < N_NODES) ? cnt[base + 2] : 0;
    int v3 = (base + 3 < N_NODES) ? cnt[base + 3] : 0;
    const int e0 = 0, e1 = v0, e2 = v0 + v1, e3 = v0 + v1 + v2;
    s[t] = e3 + v3;
    __syncthreads();
    // Hillis-Steele inclusive scan over 256 thread sums
    for (int off = 1; off < 256; off <<= 1) {
        int x = s[t];
        if (t >= off) x += s[t - off];
        __syncthreads();
        s[t] = x;
        __syncthreads();
    }
    const int texcl = (t > 0) ? s[t - 1] : 0;
    if (t == 255) parts[blockIdx.x] = s[255];
    if (base + 0 < N_NODES) offs[base + 0] = texcl + e0;
    if (base + 1 < N_NODES) offs[base + 1] = texcl + e1;
    if (base + 2 < N_NODES) offs[base + 2] = texcl + e2;
    if (base + 3 < N_NODES) offs[base + 3] = texcl + e3;
}

// Exclusive scan of the 98 block totals (single block).
__global__ __launch_bounds__(128) void sage_scan_parts(int* __restrict__ parts)
{
    __shared__ int s[128];
    const int t = threadIdx.x;
    s[t] = (t < NBLK_SCAN) ? parts[t] : 0;
    __syncthreads();
    for (int off = 1; off < 128; off <<= 1) {
        int x = s[t];
        if (t >= off) x += s[t - off];
        __syncthreads();
        s[t] = x;
        __syncthreads();
    }
    if (t < NBLK_SCAN) parts[t] = (t > 0) ? s[t - 1] : 0;
}

__global__ __launch_bounds__(256) void sage_fill(
    const int* __restrict__ ei, const int* __restrict__ offs,
    const int* __restrict__ parts, int* __restrict__ cursor,
    int* __restrict__ bucket)
{
    const int e = blockIdx.x * blockDim.x + threadIdx.x;
    if (e >= N_EDGES) return;
    const int dst = ei[e];
    const int src = ei[N_EDGES + e];
    const int pos = offs[dst] + parts[dst >> 10] + atomicAdd(&cursor[dst], 1);
    bucket[pos] = src;
}

// ---------------- gather + mean ----------------
// One 64-lane wave per node; lane c sums h[src][c] over the node's bucket.
__global__ __launch_bounds__(256) void sage_gather_mean(
    const int* __restrict__ cnt, const int* __restrict__ offs,
    const int* __restrict__ parts, const int* __restrict__ bucket,
    const float* __restrict__ h, float* __restrict__ mean)
{
    const int node = blockIdx.x * 4 + (threadIdx.x >> 6);
    const int lane = threadIdx.x & 63;
    if (node >= N_NODES) return;
    const int d = cnt[node];
    const int start = offs[node] + parts[node >> 10];
    float acc = 0.0f;
    for (int i = 0; i < d; ++i) {
        const int s = bucket[start + i];
        acc += h[(size_t)s * IN_CH + lane];
    }
    const float inv = 1.0f / (float)((d > 1) ? d : 1);
    mean[(size_t)node * IN_CH + lane] = acc * inv;
}

// ---------------- node epilogue ----------------
// 128 threads/block, thread t owns out channel t; weights in registers;
// mean/h broadcast via float4 LDS reads (4x fewer ds_read than scalar).
__global__ __launch_bounds__(128) void sage_node2(
    const float* __restrict__ h, const float* __restrict__ mean,
    const float* __restrict__ Wl, const float* __restrict__ bias,
    const float* __restrict__ Wr, float* __restrict__ out)
{
    const int t = threadIdx.x;
    float wl[IN_CH], wr[IN_CH];
#pragma unroll
    for (int k = 0; k < IN_CH; ++k) {
        wl[k] = Wl[k * HID_CH + t];
        wr[k] = Wr[k * HID_CH + t];
    }
    const float b = bias[t];

    __shared__ float4 s_m[IN_CH / 4];
    __shared__ float4 s_h[IN_CH / 4];

    for (int n = blockIdx.x; n < N_NODES; n += gridDim.x) {
        __syncthreads();
        if (t < IN_CH / 4) {
            s_m[t] = reinterpret_cast<const float4*>(mean + (size_t)n * IN_CH)[t];
            s_h[t] = reinterpret_cast<const float4*>(h + (size_t)n * IN_CH)[t];
        }
        __syncthreads();
        float acc = b;
#pragma unroll
        for (int k4 = 0; k4 < IN_CH / 4; ++k4) {
            const float4 m = s_m[k4];
            const float4 hv = s_h[k4];
            acc = fmaf(m.x, wl[k4 * 4 + 0], acc);
            acc = fmaf(m.y, wl[k4 * 4 + 1], acc);
            acc = fmaf(m.z, wl[k4 * 4 + 2], acc);
            acc = fmaf(m.w, wl[k4 * 4 + 3], acc);
            acc = fmaf(hv.x, wr[k4 * 4 + 0], acc);
            acc = fmaf(hv.y, wr[k4 * 4 + 1], acc);
            acc = fmaf(hv.z, wr[k4 * 4 + 2], acc);
            acc = fmaf(hv.w, wr[k4 * 4 + 3], acc);
        }
        out[(size_t)n * HID_CH + t] = acc;
    }
}

// ---------------- fallback (old atomic path) ----------------

__global__ __launch_bounds__(256) void sage_scatter(
    const int* __restrict__ ei, const float* __restrict__ h,
    float* __restrict__ agg, float* __restrict__ deg)
{
    const int gtid = blockIdx.x * blockDim.x + threadIdx.x;
    const int edge = gtid >> 6;
    const int lane = threadIdx.x & 63;
    if (edge >= N_EDGES) return;
    const int dst = ei[edge];
    const int src = ei[N_EDGES + edge];
    atomicAdd(&agg[(size_t)dst * IN_CH + lane], h[(size_t)src * IN_CH + lane]);
    if (lane == 0) atomicAdd(&deg[dst], 1.0f);
}

__global__ __launch_bounds__(128) void sage_node(
    const float* __restrict__ h, const float* __restrict__ agg,
    const float* __restrict__ deg, const float* __restrict__ Wl,
    const float* __restrict__ bias, const float* __restrict__ Wr,
    float* __restrict__ out)
{
    const int t = threadIdx.x;
    float wl[IN_CH], wr[IN_CH];
#pragma unroll
    for (int k = 0; k < IN_CH; ++k) {
        wl[k] = Wl[k * HID_CH + t];
        wr[k] = Wr[k * HID_CH + t];
    }
    const float b = bias[t];
    __shared__ float s_mean[IN_CH];
    __shared__ float s_h[IN_CH];
    for (int n = blockIdx.x; n < N_NODES; n += gridDim.x) {
        __syncthreads();
        if (t < IN_CH) {
            const float inv = 1.0f / fmaxf(deg[n], 1.0f);
            s_mean[t] = agg[(size_t)n * IN_CH + t] * inv;
            s_h[t] = h[(size_t)n * IN_CH + t];
        }
        __syncthreads();
        float acc = b;
#pragma unroll
        for (int k = 0; k < IN_CH; ++k) {
            acc = fmaf(s_mean[k], wl[k], acc);
            acc = fmaf(s_h[k], wr[k], acc);
        }
        out[(size_t)n * HID_CH + t] = acc;
    }
}

extern "C" void kernel_launch(void* const* d_in, const int* in_sizes, int n_in,
                              void* d_out, int out_size, void* d_ws, size_t ws_size,
                              hipStream_t stream) {
    // inputs: 0=x (unused), 1=edge_index, 2=emb_weight, 3=lin_l_w, 4=lin_l_b, 5=lin_r_w
    const int* ei = (const int*)d_in[1];
    const float* h = (const float*)d_in[2];
    const float* Wl = (const float*)d_in[3];
    const float* b = (const float*)d_in[4];
    const float* Wr = (const float*)d_in[5];
    float* out = (float*)d_out;

    // ws layout (4B elements):
    //   cnt    [0,       100000)
    //   cursor [100000,  200000)
    //   offs   [200000,  300000)
    //   parts  [300000,  300128)
    //   bucket [400000, 2000000)
    //   mean   [2000000, 8400000)  (floats)
    const size_t need = 8400000ull * 4ull;

    if (ws_size >= need) {
        int* wsi = (int*)d_ws;
        int* cnt = wsi;
        int* cursor = wsi + 100000;
        int* offs = wsi + 200000;
        int* parts = wsi + 300000;
        int* bucket = wsi + 400000;
        float* mean = (float*)(wsi + 2000000);

        hipMemsetAsync(d_ws, 0, 200000 * sizeof(int), stream);  // cnt + cursor

        sage_hist<<<(N_EDGES + 255) / 256, 256, 0, stream>>>(ei, cnt);
        sage_scan_blocks<<<NBLK_SCAN, 256, 0, stream>>>(cnt, offs, parts);
        sage_scan_parts<<<1, 128, 0, stream>>>(parts);
        sage_fill<<<(N_EDGES + 255) / 256, 256, 0, stream>>>(ei, offs, parts, cursor, bucket);
        sage_gather_mean<<<(N_NODES + 3) / 4, 256, 0, stream>>>(cnt, offs, parts, bucket, h, mean);
        sage_node2<<<2048, 128, 0, stream>>>(h, mean, Wl, b, Wr, out);
    } else {
        // fallback: atomic scatter path
        float* agg = (float*)d_ws;
        float* deg = agg + (size_t)N_NODES * IN_CH;
        hipMemsetAsync(d_ws, 0, ((size_t)N_NODES * IN_CH + N_NODES) * sizeof(float), stream);
        sage_scatter<<<(int)(((long long)N_EDGES * 64 + 255) / 256), 256, 0, stream>>>(ei, h, agg, deg);
        sage_node<<<4096, 128, 0, stream>>>(h, agg, deg, Wl, b, Wr, out);
    }
}

// Round 6
// 371.526 us; speedup vs baseline: 1.3792x; 1.1749x over previous
//
#include <hip/hip_runtime.h>

#define N_NODES 100000
#define N_EDGES 1600000
#define IN_CH 64
#define HID_CH 128

#define SCAN_ELEMS 1024                                   // elems per scan block
#define NBLK_SCAN ((N_NODES + SCAN_ELEMS - 1) / SCAN_ELEMS)  // 98

// ---------------- CSR build ----------------

__global__ __launch_bounds__(256) void sage_hist(
    const int* __restrict__ ei, int* __restrict__ cnt)
{
    const int e = blockIdx.x * blockDim.x + threadIdx.x;
    if (e >= N_EDGES) return;
    atomicAdd(&cnt[ei[e]], 1);
}

// Per-block exclusive scan: block b covers cnt[b*1024 .. b*1024+1023].
__global__ __launch_bounds__(256) void sage_scan_blocks(
    const int* __restrict__ cnt, int* __restrict__ offs, int* __restrict__ parts)
{
    __shared__ int s[256];
    const int t = threadIdx.x;
    const int base = blockIdx.x * SCAN_ELEMS + t * 4;
    int v0 = (base + 0 < N_NODES) ? cnt[base + 0] : 0;
    int v1 = (base + 1 < N_NODES) ? cnt[base + 1] : 0;
    int v2 = (base + 2 < N_NODES) ? cnt[base + 2] : 0;
    int v3 = (base + 3 < N_NODES) ? cnt[base + 3] : 0;
    const int e0 = 0, e1 = v0, e2 = v0 + v1, e3 = v0 + v1 + v2;
    s[t] = e3 + v3;
    __syncthreads();
    for (int off = 1; off < 256; off <<= 1) {
        int x = s[t];
        if (t >= off) x += s[t - off];
        __syncthreads();
        s[t] = x;
        __syncthreads();
    }
    const int texcl = (t > 0) ? s[t - 1] : 0;
    if (t == 255) parts[blockIdx.x] = s[255];
    if (base + 0 < N_NODES) offs[base + 0] = texcl + e0;
    if (base + 1 < N_NODES) offs[base + 1] = texcl + e1;
    if (base + 2 < N_NODES) offs[base + 2] = texcl + e2;
    if (base + 3 < N_NODES) offs[base + 3] = texcl + e3;
}

__global__ __launch_bounds__(128) void sage_scan_parts(int* __restrict__ parts)
{
    __shared__ int s[128];
    const int t = threadIdx.x;
    s[t] = (t < NBLK_SCAN) ? parts[t] : 0;
    __syncthreads();
    for (int off = 1; off < 128; off <<= 1) {
        int x = s[t];
        if (t >= off) x += s[t - off];
        __syncthreads();
        s[t] = x;
        __syncthreads();
    }
    if (t < NBLK_SCAN) parts[t] = (t > 0) ? s[t - 1] : 0;
}

__global__ __launch_bounds__(256) void sage_fill(
    const int* __restrict__ ei, const int* __restrict__ offs,
    const int* __restrict__ parts, int* __restrict__ cursor,
    int* __restrict__ bucket)
{
    const int e = blockIdx.x * blockDim.x + threadIdx.x;
    if (e >= N_EDGES) return;
    const int dst = ei[e];
    const int src = ei[N_EDGES + e];
    const int pos = offs[dst] + parts[dst >> 10] + atomicAdd(&cursor[dst], 1);
    bucket[pos] = src;
}

// ---------------- gather + mean ----------------
// One 64-lane wave per node; 16 lanes x float4 cover one 256B row, so the
// wave processes 4 edges concurrently (4 independent gathers in flight).
__global__ __launch_bounds__(256) void sage_gather_mean(
    const int* __restrict__ cnt, const int* __restrict__ offs,
    const int* __restrict__ parts, const int* __restrict__ bucket,
    const float* __restrict__ h, float* __restrict__ mean)
{
    const int node = blockIdx.x * 4 + (threadIdx.x >> 6);
    const int lane = threadIdx.x & 63;
    const int sub = lane >> 4;        // edge slot 0..3
    const int c4 = lane & 15;         // float4 index within the 64-ch row
    if (node >= N_NODES) return;
    const int d = cnt[node];
    const int start = offs[node] + parts[node >> 10];

    float4 acc = make_float4(0.f, 0.f, 0.f, 0.f);
    int i = 0;
#pragma unroll 2
    for (; i + 4 <= d; i += 4) {
        const int s = bucket[start + i + sub];
        const float4 v = *reinterpret_cast<const float4*>(h + (size_t)s * IN_CH + c4 * 4);
        acc.x += v.x; acc.y += v.y; acc.z += v.z; acc.w += v.w;
    }
    if (i + sub < d) {
        const int s = bucket[start + i + sub];
        const float4 v = *reinterpret_cast<const float4*>(h + (size_t)s * IN_CH + c4 * 4);
        acc.x += v.x; acc.y += v.y; acc.z += v.z; acc.w += v.w;
    }
    // reduce the 4 edge slots (lanes ^16, ^32)
    acc.x += __shfl_xor(acc.x, 16); acc.y += __shfl_xor(acc.y, 16);
    acc.z += __shfl_xor(acc.z, 16); acc.w += __shfl_xor(acc.w, 16);
    acc.x += __shfl_xor(acc.x, 32); acc.y += __shfl_xor(acc.y, 32);
    acc.z += __shfl_xor(acc.z, 32); acc.w += __shfl_xor(acc.w, 32);

    if (sub == 0) {
        const float inv = 1.0f / (float)((d > 1) ? d : 1);
        float4 r;
        r.x = acc.x * inv; r.y = acc.y * inv; r.z = acc.z * inv; r.w = acc.w * inv;
        reinterpret_cast<float4*>(mean + (size_t)node * IN_CH)[c4] = r;
    }
}

// ---------------- node epilogue ----------------
// Thread t owns out channel t; weights in VGPRs. Per-node mean/h rows are
// read through BLOCK-UNIFORM pointers -> compiler emits s_load (SMEM path,
// SGPR operand into v_fma). No LDS, no syncthreads.
__global__ __launch_bounds__(128) void sage_node2(
    const float* __restrict__ h, const float* __restrict__ mean,
    const float* __restrict__ Wl, const float* __restrict__ bias,
    const float* __restrict__ Wr, float* __restrict__ out)
{
    const int t = threadIdx.x;
    float wl[IN_CH], wr[IN_CH];
#pragma unroll
    for (int k = 0; k < IN_CH; ++k) {
        wl[k] = Wl[k * HID_CH + t];
        wr[k] = Wr[k * HID_CH + t];
    }
    const float b = bias[t];

    for (int n = blockIdx.x; n < N_NODES; n += gridDim.x) {
        const float* __restrict__ mrow = mean + (size_t)n * IN_CH;
        const float* __restrict__ hrow = h + (size_t)n * IN_CH;
        float acc = b;
#pragma unroll
        for (int k = 0; k < IN_CH; ++k) acc = fmaf(mrow[k], wl[k], acc);
#pragma unroll
        for (int k = 0; k < IN_CH; ++k) acc = fmaf(hrow[k], wr[k], acc);
        out[(size_t)n * HID_CH + t] = acc;
    }
}

// ---------------- fallback (old atomic path) ----------------

__global__ __launch_bounds__(256) void sage_scatter(
    const int* __restrict__ ei, const float* __restrict__ h,
    float* __restrict__ agg, float* __restrict__ deg)
{
    const int gtid = blockIdx.x * blockDim.x + threadIdx.x;
    const int edge = gtid >> 6;
    const int lane = threadIdx.x & 63;
    if (edge >= N_EDGES) return;
    const int dst = ei[edge];
    const int src = ei[N_EDGES + edge];
    atomicAdd(&agg[(size_t)dst * IN_CH + lane], h[(size_t)src * IN_CH + lane]);
    if (lane == 0) atomicAdd(&deg[dst], 1.0f);
}

__global__ __launch_bounds__(128) void sage_node(
    const float* __restrict__ h, const float* __restrict__ agg,
    const float* __restrict__ deg, const float* __restrict__ Wl,
    const float* __restrict__ bias, const float* __restrict__ Wr,
    float* __restrict__ out)
{
    const int t = threadIdx.x;
    float wl[IN_CH], wr[IN_CH];
#pragma unroll
    for (int k = 0; k < IN_CH; ++k) {
        wl[k] = Wl[k * HID_CH + t];
        wr[k] = Wr[k * HID_CH + t];
    }
    const float b = bias[t];
    __shared__ float s_mean[IN_CH];
    __shared__ float s_h[IN_CH];
    for (int n = blockIdx.x; n < N_NODES; n += gridDim.x) {
        __syncthreads();
        if (t < IN_CH) {
            const float inv = 1.0f / fmaxf(deg[n], 1.0f);
            s_mean[t] = agg[(size_t)n * IN_CH + t] * inv;
            s_h[t] = h[(size_t)n * IN_CH + t];
        }
        __syncthreads();
        float acc = b;
#pragma unroll
        for (int k = 0; k < IN_CH; ++k) {
            acc = fmaf(s_mean[k], wl[k], acc);
            acc = fmaf(s_h[k], wr[k], acc);
        }
        out[(size_t)n * HID_CH + t] = acc;
    }
}

extern "C" void kernel_launch(void* const* d_in, const int* in_sizes, int n_in,
                              void* d_out, int out_size, void* d_ws, size_t ws_size,
                              hipStream_t stream) {
    // inputs: 0=x (unused), 1=edge_index, 2=emb_weight, 3=lin_l_w, 4=lin_l_b, 5=lin_r_w
    const int* ei = (const int*)d_in[1];
    const float* h = (const float*)d_in[2];
    const float* Wl = (const float*)d_in[3];
    const float* b = (const float*)d_in[4];
    const float* Wr = (const float*)d_in[5];
    float* out = (float*)d_out;

    // ws layout (4B elements):
    //   cnt    [0,       100000)
    //   cursor [100000,  200000)
    //   offs   [200000,  300000)
    //   parts  [300000,  300128)
    //   bucket [400000, 2000000)
    //   mean   [2000000, 8400000)  (floats)
    const size_t need = 8400000ull * 4ull;

    if (ws_size >= need) {
        int* wsi = (int*)d_ws;
        int* cnt = wsi;
        int* cursor = wsi + 100000;
        int* offs = wsi + 200000;
        int* parts = wsi + 300000;
        int* bucket = wsi + 400000;
        float* mean = (float*)(wsi + 2000000);

        hipMemsetAsync(d_ws, 0, 200000 * sizeof(int), stream);  // cnt + cursor

        sage_hist<<<(N_EDGES + 255) / 256, 256, 0, stream>>>(ei, cnt);
        sage_scan_blocks<<<NBLK_SCAN, 256, 0, stream>>>(cnt, offs, parts);
        sage_scan_parts<<<1, 128, 0, stream>>>(parts);
        sage_fill<<<(N_EDGES + 255) / 256, 256, 0, stream>>>(ei, offs, parts, cursor, bucket);
        sage_gather_mean<<<(N_NODES + 3) / 4, 256, 0, stream>>>(cnt, offs, parts, bucket, h, mean);
        sage_node2<<<2048, 128, 0, stream>>>(h, mean, Wl, b, Wr, out);
    } else {
        // fallback: atomic scatter path
        float* agg = (float*)d_ws;
        float* deg = agg + (size_t)N_NODES * IN_CH;
        hipMemsetAsync(d_ws, 0, ((size_t)N_NODES * IN_CH + N_NODES) * sizeof(float), stream);
        sage_scatter<<<(int)(((long long)N_EDGES * 64 + 255) / 256), 256, 0, stream>>>(ei, h, agg, deg);
        sage_node<<<4096, 128, 0, stream>>>(h, agg, deg, Wl, b, Wr, out);
    }
}

// Round 7
// 256.788 us; speedup vs baseline: 1.9955x; 1.4468x over previous
//
#include <hip/hip_runtime.h>

#define N_NODES 100000
#define N_EDGES 1600000
#define IN_CH 64
#define HID_CH 128

#define SCAN_ELEMS 1024                                   // elems per scan block
#define NBLK_SCAN ((N_NODES + SCAN_ELEMS - 1) / SCAN_ELEMS)  // 98

typedef __attribute__((ext_vector_type(8))) short bf16x8;  // 8 bf16 = 4 VGPR
typedef __attribute__((ext_vector_type(4))) float f32x4;

static __device__ __forceinline__ unsigned short f2bf(float f) {
    union { float f; unsigned int u; } v; v.f = f;
    const unsigned int u = v.u;
    return (unsigned short)((u + 0x7FFFu + ((u >> 16) & 1u)) >> 16);  // RNE
}

// ---------------- CSR build ----------------

__global__ __launch_bounds__(256) void sage_hist(
    const int* __restrict__ ei, int* __restrict__ cnt)
{
    const int e = blockIdx.x * blockDim.x + threadIdx.x;
    if (e >= N_EDGES) return;
    atomicAdd(&cnt[ei[e]], 1);
}

__global__ __launch_bounds__(256) void sage_scan_blocks(
    const int* __restrict__ cnt, int* __restrict__ offs, int* __restrict__ parts)
{
    __shared__ int s[256];
    const int t = threadIdx.x;
    const int base = blockIdx.x * SCAN_ELEMS + t * 4;
    int v0 = (base + 0 < N_NODES) ? cnt[base + 0] : 0;
    int v1 = (base + 1 < N_NODES) ? cnt[base + 1] : 0;
    int v2 = (base + 2 < N_NODES) ? cnt[base + 2] : 0;
    int v3 = (base + 3 < N_NODES) ? cnt[base + 3] : 0;
    const int e0 = 0, e1 = v0, e2 = v0 + v1, e3 = v0 + v1 + v2;
    s[t] = e3 + v3;
    __syncthreads();
    for (int off = 1; off < 256; off <<= 1) {
        int x = s[t];
        if (t >= off) x += s[t - off];
        __syncthreads();
        s[t] = x;
        __syncthreads();
    }
    const int texcl = (t > 0) ? s[t - 1] : 0;
    if (t == 255) parts[blockIdx.x] = s[255];
    if (base + 0 < N_NODES) offs[base + 0] = texcl + e0;
    if (base + 1 < N_NODES) offs[base + 1] = texcl + e1;
    if (base + 2 < N_NODES) offs[base + 2] = texcl + e2;
    if (base + 3 < N_NODES) offs[base + 3] = texcl + e3;
}

__global__ __launch_bounds__(128) void sage_scan_parts(int* __restrict__ parts)
{
    __shared__ int s[128];
    const int t = threadIdx.x;
    s[t] = (t < NBLK_SCAN) ? parts[t] : 0;
    __syncthreads();
    for (int off = 1; off < 128; off <<= 1) {
        int x = s[t];
        if (t >= off) x += s[t - off];
        __syncthreads();
        s[t] = x;
        __syncthreads();
    }
    if (t < NBLK_SCAN) parts[t] = (t > 0) ? s[t - 1] : 0;
}

__global__ __launch_bounds__(256) void sage_fill(
    const int* __restrict__ ei, const int* __restrict__ offs,
    const int* __restrict__ parts, int* __restrict__ cursor,
    int* __restrict__ bucket)
{
    const int e = blockIdx.x * blockDim.x + threadIdx.x;
    if (e >= N_EDGES) return;
    const int dst = ei[e];
    const int src = ei[N_EDGES + e];
    const int pos = offs[dst] + parts[dst >> 10] + atomicAdd(&cursor[dst], 1);
    bucket[pos] = src;
}

// ---------------- bf16 conversions ----------------

__global__ __launch_bounds__(256) void sage_cvt_h(
    const float* __restrict__ h, unsigned short* __restrict__ hb)
{
    const int n4 = N_NODES * IN_CH / 4;
    for (int i = blockIdx.x * blockDim.x + threadIdx.x; i < n4;
         i += gridDim.x * blockDim.x) {
        const float4 v = reinterpret_cast<const float4*>(h)[i];
        ushort4 o;
        o.x = f2bf(v.x); o.y = f2bf(v.y); o.z = f2bf(v.z); o.w = f2bf(v.w);
        reinterpret_cast<ushort4*>(hb)[i] = o;
    }
}

// Bt[n][k] = bf16( k<64 ? Wl[k][n] : Wr[k-64][n] )  -- [128][128]
__global__ __launch_bounds__(256) void sage_cvt_w(
    const float* __restrict__ Wl, const float* __restrict__ Wr,
    unsigned short* __restrict__ Bt)
{
    const int i = blockIdx.x * blockDim.x + threadIdx.x;
    if (i >= HID_CH * HID_CH) return;
    const int n = i >> 7, k = i & 127;
    const float v = (k < 64) ? Wl[k * HID_CH + n] : Wr[(k - 64) * HID_CH + n];
    Bt[i] = f2bf(v);
}

// ---------------- gather + mean (writes bf16) ----------------
// One 64-lane wave per node; 16 lanes x float4 cover one 256B row, so the
// wave processes 4 edges concurrently (4 independent gathers in flight).
__global__ __launch_bounds__(256) void sage_gather_mean(
    const int* __restrict__ cnt, const int* __restrict__ offs,
    const int* __restrict__ parts, const int* __restrict__ bucket,
    const float* __restrict__ h, unsigned short* __restrict__ meanb)
{
    const int node = blockIdx.x * 4 + (threadIdx.x >> 6);
    const int lane = threadIdx.x & 63;
    const int sub = lane >> 4;        // edge slot 0..3
    const int c4 = lane & 15;         // float4 index within the 64-ch row
    if (node >= N_NODES) return;
    const int d = cnt[node];
    const int start = offs[node] + parts[node >> 10];

    float4 acc = make_float4(0.f, 0.f, 0.f, 0.f);
    int i = 0;
#pragma unroll 2
    for (; i + 4 <= d; i += 4) {
        const int s = bucket[start + i + sub];
        const float4 v = *reinterpret_cast<const float4*>(h + (size_t)s * IN_CH + c4 * 4);
        acc.x += v.x; acc.y += v.y; acc.z += v.z; acc.w += v.w;
    }
    if (i + sub < d) {
        const int s = bucket[start + i + sub];
        const float4 v = *reinterpret_cast<const float4*>(h + (size_t)s * IN_CH + c4 * 4);
        acc.x += v.x; acc.y += v.y; acc.z += v.z; acc.w += v.w;
    }
    acc.x += __shfl_xor(acc.x, 16); acc.y += __shfl_xor(acc.y, 16);
    acc.z += __shfl_xor(acc.z, 16); acc.w += __shfl_xor(acc.w, 16);
    acc.x += __shfl_xor(acc.x, 32); acc.y += __shfl_xor(acc.y, 32);
    acc.z += __shfl_xor(acc.z, 32); acc.w += __shfl_xor(acc.w, 32);

    if (sub == 0) {
        const float inv = 1.0f / (float)((d > 1) ? d : 1);
        ushort4 r;
        r.x = f2bf(acc.x * inv); r.y = f2bf(acc.y * inv);
        r.z = f2bf(acc.z * inv); r.w = f2bf(acc.w * inv);
        reinterpret_cast<ushort4*>(meanb + (size_t)node * IN_CH)[c4] = r;
    }
}

// ---------------- MFMA epilogue ----------------
// out[100000 x 128] = concat(meanb, hb) @ Bt^T + bias, fp32 accumulate.
// One wave per 16-node tile; 8 col-tiles x 4 k-tiles = 32 MFMA per wave.
// Layouts (m89-verified): A row=lane&15, k=(lane>>4)*8+j (contiguous 16B);
// B col=lane&15, k likewise (Bt stored [n][k] so loads are contiguous);
// C col=lane&15, row=(lane>>4)*4+reg.
__global__ __launch_bounds__(256) void sage_mfma(
    const unsigned short* __restrict__ meanb, const unsigned short* __restrict__ hb,
    const unsigned short* __restrict__ Bt, const float* __restrict__ bias,
    float* __restrict__ out)
{
    const int wid = (blockIdx.x * blockDim.x + threadIdx.x) >> 6;  // m-tile
    if (wid >= N_NODES / 16) return;
    const int lane = threadIdx.x & 63;
    const int lrow = lane & 15;
    const int lk8 = (lane >> 4) * 8;
    const int node0 = wid * 16;

    bf16x8 a[4];
    {
        const unsigned short* am = meanb + (size_t)(node0 + lrow) * IN_CH;
        const unsigned short* ah = hb + (size_t)(node0 + lrow) * IN_CH;
        a[0] = *reinterpret_cast<const bf16x8*>(am + lk8);
        a[1] = *reinterpret_cast<const bf16x8*>(am + 32 + lk8);
        a[2] = *reinterpret_cast<const bf16x8*>(ah + lk8);
        a[3] = *reinterpret_cast<const bf16x8*>(ah + 32 + lk8);
    }

    f32x4 acc[8];
#pragma unroll
    for (int ct = 0; ct < 8; ++ct) {
        acc[ct] = (f32x4){0.f, 0.f, 0.f, 0.f};
#pragma unroll
        for (int kk = 0; kk < 4; ++kk) {
            const bf16x8 b = *reinterpret_cast<const bf16x8*>(
                Bt + (size_t)(ct * 16 + lrow) * 128 + kk * 32 + lk8);
            acc[ct] = __builtin_amdgcn_mfma_f32_16x16x32_bf16(a[kk], b, acc[ct], 0, 0, 0);
        }
    }

#pragma unroll
    for (int ct = 0; ct < 8; ++ct) {
        const int ch = ct * 16 + lrow;
        const float bv = bias[ch];
#pragma unroll
        for (int r = 0; r < 4; ++r) {
            const int node = node0 + (lane >> 4) * 4 + r;
            out[(size_t)node * HID_CH + ch] = acc[ct][r] + bv;
        }
    }
}

// ---------------- fallback (old atomic path) ----------------

__global__ __launch_bounds__(256) void sage_scatter(
    const int* __restrict__ ei, const float* __restrict__ h,
    float* __restrict__ agg, float* __restrict__ deg)
{
    const int gtid = blockIdx.x * blockDim.x + threadIdx.x;
    const int edge = gtid >> 6;
    const int lane = threadIdx.x & 63;
    if (edge >= N_EDGES) return;
    const int dst = ei[edge];
    const int src = ei[N_EDGES + edge];
    atomicAdd(&agg[(size_t)dst * IN_CH + lane], h[(size_t)src * IN_CH + lane]);
    if (lane == 0) atomicAdd(&deg[dst], 1.0f);
}

__global__ __launch_bounds__(128) void sage_node(
    const float* __restrict__ h, const float* __restrict__ agg,
    const float* __restrict__ deg, const float* __restrict__ Wl,
    const float* __restrict__ bias, const float* __restrict__ Wr,
    float* __restrict__ out)
{
    const int t = threadIdx.x;
    float wl[IN_CH], wr[IN_CH];
#pragma unroll
    for (int k = 0; k < IN_CH; ++k) {
        wl[k] = Wl[k * HID_CH + t];
        wr[k] = Wr[k * HID_CH + t];
    }
    const float b = bias[t];
    __shared__ float s_mean[IN_CH];
    __shared__ float s_h[IN_CH];
    for (int n = blockIdx.x; n < N_NODES; n += gridDim.x) {
        __syncthreads();
        if (t < IN_CH) {
            const float inv = 1.0f / fmaxf(deg[n], 1.0f);
            s_mean[t] = agg[(size_t)n * IN_CH + t] * inv;
            s_h[t] = h[(size_t)n * IN_CH + t];
        }
        __syncthreads();
        float acc = b;
#pragma unroll
        for (int k = 0; k < IN_CH; ++k) {
            acc = fmaf(s_mean[k], wl[k], acc);
            acc = fmaf(s_h[k], wr[k], acc);
        }
        out[(size_t)n * HID_CH + t] = acc;
    }
}

extern "C" void kernel_launch(void* const* d_in, const int* in_sizes, int n_in,
                              void* d_out, int out_size, void* d_ws, size_t ws_size,
                              hipStream_t stream) {
    // inputs: 0=x (unused), 1=edge_index, 2=emb_weight, 3=lin_l_w, 4=lin_l_b, 5=lin_r_w
    const int* ei = (const int*)d_in[1];
    const float* h = (const float*)d_in[2];
    const float* Wl = (const float*)d_in[3];
    const float* b = (const float*)d_in[4];
    const float* Wr = (const float*)d_in[5];
    float* out = (float*)d_out;

    // ws layout (4B elements):
    //   cnt    [0,       100000)
    //   cursor [100000,  200000)
    //   offs   [200000,  300000)
    //   parts  [300000,  300128)
    //   Bt     [300200,  308392)   (bf16 128x128 = 8192 dwords)
    //   bucket [400000, 2000000)
    //   meanb  [2000000, 5200000)  (bf16 100000x64 = 3.2M dwords)
    //   hb     [5200000, 8400000)  (bf16 100000x64 = 3.2M dwords)
    const size_t need = 8400000ull * 4ull;

    if (ws_size >= need) {
        int* wsi = (int*)d_ws;
        int* cnt = wsi;
        int* cursor = wsi + 100000;
        int* offs = wsi + 200000;
        int* parts = wsi + 300000;
        unsigned short* Bt = (unsigned short*)(wsi + 300200);
        int* bucket = wsi + 400000;
        unsigned short* meanb = (unsigned short*)(wsi + 2000000);
        unsigned short* hb = (unsigned short*)(wsi + 5200000);

        hipMemsetAsync(d_ws, 0, 200000 * sizeof(int), stream);  // cnt + cursor

        sage_hist<<<(N_EDGES + 255) / 256, 256, 0, stream>>>(ei, cnt);
        sage_scan_blocks<<<NBLK_SCAN, 256, 0, stream>>>(cnt, offs, parts);
        sage_scan_parts<<<1, 128, 0, stream>>>(parts);
        sage_fill<<<(N_EDGES + 255) / 256, 256, 0, stream>>>(ei, offs, parts, cursor, bucket);
        sage_cvt_h<<<2048, 256, 0, stream>>>(h, hb);
        sage_cvt_w<<<(HID_CH * HID_CH + 255) / 256, 256, 0, stream>>>(Wl, Wr, Bt);
        sage_gather_mean<<<(N_NODES + 3) / 4, 256, 0, stream>>>(cnt, offs, parts, bucket, h, meanb);
        sage_mfma<<<(N_NODES / 16 + 3) / 4, 256, 0, stream>>>(meanb, hb, Bt, b, out);
    } else {
        // fallback: atomic scatter path
        float* agg = (float*)d_ws;
        float* deg = agg + (size_t)N_NODES * IN_CH;
        hipMemsetAsync(d_ws, 0, ((size_t)N_NODES * IN_CH + N_NODES) * sizeof(float), stream);
        sage_scatter<<<(int)(((long long)N_EDGES * 64 + 255) / 256), 256, 0, stream>>>(ei, h, agg, deg);
        sage_node<<<4096, 128, 0, stream>>>(h, agg, deg, Wl, b, Wr, out);
    }
}

// Round 8
// 230.000 us; speedup vs baseline: 2.2279x; 1.1165x over previous
//
#include <hip/hip_runtime.h>

#define N_NODES 100000
#define N_EDGES 1600000
#define IN_CH 64
#define HID_CH 128

#define SCAN_ELEMS 1024                                   // nodes per bin
#define NBLK_SCAN ((N_NODES + SCAN_ELEMS - 1) / SCAN_ELEMS)  // 98 bins
#define EPB 2048                                          // edges per stage block

typedef __attribute__((ext_vector_type(8))) short bf16x8;  // 8 bf16 = 4 VGPR
typedef __attribute__((ext_vector_type(4))) float f32x4;

static __device__ __forceinline__ unsigned short f2bf(float f) {
    union { float f; unsigned int u; } v; v.f = f;
    const unsigned int u = v.u;
    return (unsigned short)((u + 0x7FFFu + ((u >> 16) & 1u)) >> 16);  // RNE
}

// ---------------- CSR build ----------------

__global__ __launch_bounds__(256) void sage_hist(
    const int* __restrict__ ei, int* __restrict__ cnt)
{
    const int e = blockIdx.x * blockDim.x + threadIdx.x;
    if (e >= N_EDGES) return;
    atomicAdd(&cnt[ei[e]], 1);
}

// Per-bin exclusive scan: bin b covers cnt[b*1024 .. b*1024+1023].
// offs = local exclusive prefix within bin; parts[b] = bin total.
__global__ __launch_bounds__(256) void sage_scan_blocks(
    const int* __restrict__ cnt, int* __restrict__ offs, int* __restrict__ parts)
{
    __shared__ int s[256];
    const int t = threadIdx.x;
    const int base = blockIdx.x * SCAN_ELEMS + t * 4;
    int v0 = (base + 0 < N_NODES) ? cnt[base + 0] : 0;
    int v1 = (base + 1 < N_NODES) ? cnt[base + 1] : 0;
    int v2 = (base + 2 < N_NODES) ? cnt[base + 2] : 0;
    int v3 = (base + 3 < N_NODES) ? cnt[base + 3] : 0;
    const int e0 = 0, e1 = v0, e2 = v0 + v1, e3 = v0 + v1 + v2;
    s[t] = e3 + v3;
    __syncthreads();
    for (int off = 1; off < 256; off <<= 1) {
        int x = s[t];
        if (t >= off) x += s[t - off];
        __syncthreads();
        s[t] = x;
        __syncthreads();
    }
    const int texcl = (t > 0) ? s[t - 1] : 0;
    if (t == 255) parts[blockIdx.x] = s[255];
    if (base + 0 < N_NODES) offs[base + 0] = texcl + e0;
    if (base + 1 < N_NODES) offs[base + 1] = texcl + e1;
    if (base + 2 < N_NODES) offs[base + 2] = texcl + e2;
    if (base + 3 < N_NODES) offs[base + 3] = texcl + e3;
}

// Exclusive scan of the 98 bin totals -> bin base offsets.
__global__ __launch_bounds__(128) void sage_scan_parts(int* __restrict__ parts)
{
    __shared__ int s[128];
    const int t = threadIdx.x;
    s[t] = (t < NBLK_SCAN) ? parts[t] : 0;
    __syncthreads();
    for (int off = 1; off < 128; off <<= 1) {
        int x = s[t];
        if (t >= off) x += s[t - off];
        __syncthreads();
        s[t] = x;
        __syncthreads();
    }
    if (t < NBLK_SCAN) parts[t] = (t > 0) ? s[t - 1] : 0;
}

// Partition edges into 98 bin regions of `stage` as (dst,src) pairs.
// LDS bin histogram -> one global atomic per bin per block reserves a
// contiguous run -> writes are single-writer runs (near-full-line).
__global__ __launch_bounds__(256) void sage_stage(
    const int* __restrict__ ei, const int* __restrict__ parts,
    int* __restrict__ bin_cursor, int2* __restrict__ stage)
{
    __shared__ int s_cnt[NBLK_SCAN];
    __shared__ int s_base[NBLK_SCAN];
    const int t = threadIdx.x;
    const int e0 = blockIdx.x * EPB;
    for (int i = t; i < NBLK_SCAN; i += 256) s_cnt[i] = 0;
    __syncthreads();
    int dst[8], src[8], bin[8];
#pragma unroll
    for (int k = 0; k < 8; ++k) {
        const int e = e0 + k * 256 + t;
        if (e < N_EDGES) {
            dst[k] = ei[e];
            src[k] = ei[N_EDGES + e];
            bin[k] = dst[k] >> 10;
            atomicAdd(&s_cnt[bin[k]], 1);
        } else bin[k] = -1;
    }
    __syncthreads();
    for (int i = t; i < NBLK_SCAN; i += 256) {
        const int c = s_cnt[i];
        s_base[i] = (c > 0) ? (parts[i] + atomicAdd(&bin_cursor[i], c)) : 0;
        s_cnt[i] = 0;
    }
    __syncthreads();
#pragma unroll
    for (int k = 0; k < 8; ++k) {
        if (bin[k] >= 0) {
            const int p = s_base[bin[k]] + atomicAdd(&s_cnt[bin[k]], 1);
            stage[p] = make_int2(dst[k], src[k]);
        }
    }
}

// One block per bin: scatter staged pairs to final CSR order. All writes land
// in the bin's ~65KB window (single block/XCD -> full-line writebacks);
// per-node cursors are LDS atomics.
__global__ __launch_bounds__(256) void sage_bucket(
    const int2* __restrict__ stage, const int* __restrict__ parts,
    const int* __restrict__ offs, int* __restrict__ bucket)
{
    __shared__ int s_cur[SCAN_ELEMS];
    const int b = blockIdx.x;
    const int t = threadIdx.x;
    for (int i = t; i < SCAN_ELEMS; i += 256) s_cur[i] = 0;
    __syncthreads();
    const int start = parts[b];
    const int end = (b + 1 < NBLK_SCAN) ? parts[b + 1] : N_EDGES;
    for (int i = start + t; i < end; i += 256) {
        const int2 p = stage[i];
        const int pos = start + offs[p.x] + atomicAdd(&s_cur[p.x & (SCAN_ELEMS - 1)], 1);
        bucket[pos] = p.y;
    }
}

// ---------------- bf16 weight pack ----------------
// Bt[n][k] = bf16( k<64 ? Wl[k][n] : Wr[k-64][n] )  -- [128][128]
__global__ __launch_bounds__(256) void sage_cvt_w(
    const float* __restrict__ Wl, const float* __restrict__ Wr,
    unsigned short* __restrict__ Bt)
{
    const int i = blockIdx.x * blockDim.x + threadIdx.x;
    if (i >= HID_CH * HID_CH) return;
    const int n = i >> 7, k = i & 127;
    const float v = (k < 64) ? Wl[k * HID_CH + n] : Wr[(k - 64) * HID_CH + n];
    Bt[i] = f2bf(v);
}

// ---------------- gather + mean (writes bf16) ----------------
// One 64-lane wave per node; 16 lanes x float4 cover one 256B row, so the
// wave processes 4 edges concurrently (4 independent gathers in flight).
__global__ __launch_bounds__(256) void sage_gather_mean(
    const int* __restrict__ cnt, const int* __restrict__ offs,
    const int* __restrict__ parts, const int* __restrict__ bucket,
    const float* __restrict__ h, unsigned short* __restrict__ meanb)
{
    const int node = blockIdx.x * 4 + (threadIdx.x >> 6);
    const int lane = threadIdx.x & 63;
    const int sub = lane >> 4;        // edge slot 0..3
    const int c4 = lane & 15;         // float4 index within the 64-ch row
    if (node >= N_NODES) return;
    const int d = cnt[node];
    const int start = offs[node] + parts[node >> 10];

    float4 acc = make_float4(0.f, 0.f, 0.f, 0.f);
    int i = 0;
#pragma unroll 2
    for (; i + 4 <= d; i += 4) {
        const int s = bucket[start + i + sub];
        const float4 v = *reinterpret_cast<const float4*>(h + (size_t)s * IN_CH + c4 * 4);
        acc.x += v.x; acc.y += v.y; acc.z += v.z; acc.w += v.w;
    }
    if (i + sub < d) {
        const int s = bucket[start + i + sub];
        const float4 v = *reinterpret_cast<const float4*>(h + (size_t)s * IN_CH + c4 * 4);
        acc.x += v.x; acc.y += v.y; acc.z += v.z; acc.w += v.w;
    }
    acc.x += __shfl_xor(acc.x, 16); acc.y += __shfl_xor(acc.y, 16);
    acc.z += __shfl_xor(acc.z, 16); acc.w += __shfl_xor(acc.w, 16);
    acc.x += __shfl_xor(acc.x, 32); acc.y += __shfl_xor(acc.y, 32);
    acc.z += __shfl_xor(acc.z, 32); acc.w += __shfl_xor(acc.w, 32);

    if (sub == 0) {
        const float inv = 1.0f / (float)((d > 1) ? d : 1);
        ushort4 r;
        r.x = f2bf(acc.x * inv); r.y = f2bf(acc.y * inv);
        r.z = f2bf(acc.z * inv); r.w = f2bf(acc.w * inv);
        reinterpret_cast<ushort4*>(meanb + (size_t)node * IN_CH)[c4] = r;
    }
}

// ---------------- MFMA epilogue ----------------
// out[100000 x 128] = concat(meanb, bf16(h)) @ Bt^T + bias, fp32 accumulate.
// One wave per 16-node tile; 8 col-tiles x 4 k-tiles = 32 MFMA per wave.
// h is read fp32 and converted in-register (cvt_h kernel eliminated).
__global__ __launch_bounds__(256) void sage_mfma(
    const unsigned short* __restrict__ meanb, const float* __restrict__ h,
    const unsigned short* __restrict__ Bt, const float* __restrict__ bias,
    float* __restrict__ out)
{
    const int wid = (blockIdx.x * blockDim.x + threadIdx.x) >> 6;  // m-tile
    if (wid >= N_NODES / 16) return;
    const int lane = threadIdx.x & 63;
    const int lrow = lane & 15;
    const int lk8 = (lane >> 4) * 8;
    const int node0 = wid * 16;

    bf16x8 a[4];
    {
        const unsigned short* am = meanb + (size_t)(node0 + lrow) * IN_CH;
        a[0] = *reinterpret_cast<const bf16x8*>(am + lk8);
        a[1] = *reinterpret_cast<const bf16x8*>(am + 32 + lk8);
        const float* ah = h + (size_t)(node0 + lrow) * IN_CH;
        const float4 f0 = *reinterpret_cast<const float4*>(ah + lk8);
        const float4 f1 = *reinterpret_cast<const float4*>(ah + lk8 + 4);
        const float4 f2 = *reinterpret_cast<const float4*>(ah + 32 + lk8);
        const float4 f3 = *reinterpret_cast<const float4*>(ah + 32 + lk8 + 4);
        bf16x8 a2, a3;
        a2[0] = (short)f2bf(f0.x); a2[1] = (short)f2bf(f0.y);
        a2[2] = (short)f2bf(f0.z); a2[3] = (short)f2bf(f0.w);
        a2[4] = (short)f2bf(f1.x); a2[5] = (short)f2bf(f1.y);
        a2[6] = (short)f2bf(f1.z); a2[7] = (short)f2bf(f1.w);
        a3[0] = (short)f2bf(f2.x); a3[1] = (short)f2bf(f2.y);
        a3[2] = (short)f2bf(f2.z); a3[3] = (short)f2bf(f2.w);
        a3[4] = (short)f2bf(f3.x); a3[5] = (short)f2bf(f3.y);
        a3[6] = (short)f2bf(f3.z); a3[7] = (short)f2bf(f3.w);
        a[2] = a2; a[3] = a3;
    }

    f32x4 acc[8];
#pragma unroll
    for (int ct = 0; ct < 8; ++ct) {
        acc[ct] = (f32x4){0.f, 0.f, 0.f, 0.f};
#pragma unroll
        for (int kk = 0; kk < 4; ++kk) {
            const bf16x8 b = *reinterpret_cast<const bf16x8*>(
                Bt + (size_t)(ct * 16 + lrow) * 128 + kk * 32 + lk8);
            acc[ct] = __builtin_amdgcn_mfma_f32_16x16x32_bf16(a[kk], b, acc[ct], 0, 0, 0);
        }
    }

#pragma unroll
    for (int ct = 0; ct < 8; ++ct) {
        const int ch = ct * 16 + lrow;
        const float bv = bias[ch];
#pragma unroll
        for (int r = 0; r < 4; ++r) {
            const int node = node0 + (lane >> 4) * 4 + r;
            out[(size_t)node * HID_CH + ch] = acc[ct][r] + bv;
        }
    }
}

// ---------------- fallback (old atomic path) ----------------

__global__ __launch_bounds__(256) void sage_scatter(
    const int* __restrict__ ei, const float* __restrict__ h,
    float* __restrict__ agg, float* __restrict__ deg)
{
    const int gtid = blockIdx.x * blockDim.x + threadIdx.x;
    const int edge = gtid >> 6;
    const int lane = threadIdx.x & 63;
    if (edge >= N_EDGES) return;
    const int dst = ei[edge];
    const int src = ei[N_EDGES + edge];
    atomicAdd(&agg[(size_t)dst * IN_CH + lane], h[(size_t)src * IN_CH + lane]);
    if (lane == 0) atomicAdd(&deg[dst], 1.0f);
}

__global__ __launch_bounds__(128) void sage_node(
    const float* __restrict__ h, const float* __restrict__ agg,
    const float* __restrict__ deg, const float* __restrict__ Wl,
    const float* __restrict__ bias, const float* __restrict__ Wr,
    float* __restrict__ out)
{
    const int t = threadIdx.x;
    float wl[IN_CH], wr[IN_CH];
#pragma unroll
    for (int k = 0; k < IN_CH; ++k) {
        wl[k] = Wl[k * HID_CH + t];
        wr[k] = Wr[k * HID_CH + t];
    }
    const float b = bias[t];
    __shared__ float s_mean[IN_CH];
    __shared__ float s_h[IN_CH];
    for (int n = blockIdx.x; n < N_NODES; n += gridDim.x) {
        __syncthreads();
        if (t < IN_CH) {
            const float inv = 1.0f / fmaxf(deg[n], 1.0f);
            s_mean[t] = agg[(size_t)n * IN_CH + t] * inv;
            s_h[t] = h[(size_t)n * IN_CH + t];
        }
        __syncthreads();
        float acc = b;
#pragma unroll
        for (int k = 0; k < IN_CH; ++k) {
            acc = fmaf(s_mean[k], wl[k], acc);
            acc = fmaf(s_h[k], wr[k], acc);
        }
        out[(size_t)n * HID_CH + t] = acc;
    }
}

extern "C" void kernel_launch(void* const* d_in, const int* in_sizes, int n_in,
                              void* d_out, int out_size, void* d_ws, size_t ws_size,
                              hipStream_t stream) {
    // inputs: 0=x (unused), 1=edge_index, 2=emb_weight, 3=lin_l_w, 4=lin_l_b, 5=lin_r_w
    const int* ei = (const int*)d_in[1];
    const float* h = (const float*)d_in[2];
    const float* Wl = (const float*)d_in[3];
    const float* b = (const float*)d_in[4];
    const float* Wr = (const float*)d_in[5];
    float* out = (float*)d_out;

    // ws layout (4B elements):
    //   cnt        [0,       100000)
    //   cursor     [100000,  200000)   (fallback only)
    //   offs       [200000,  300000)
    //   parts      [300000,  300128)
    //   bin_cursor [300128,  300256)
    //   Bt         [300300,  308492)   (bf16 128x128 = 8192 dwords)
    //   bucket     [400000, 2000000)
    //   meanb      [2000000, 5200000)  (bf16 100000x64 = 3.2M dwords)
    //   stage      [5200000, 8400000)  (int2 x 1.6M = 3.2M dwords)
    const size_t need = 8400000ull * 4ull;

    if (ws_size >= need) {
        int* wsi = (int*)d_ws;
        int* cnt = wsi;
        int* offs = wsi + 200000;
        int* parts = wsi + 300000;
        int* bin_cursor = wsi + 300128;
        unsigned short* Bt = (unsigned short*)(wsi + 300300);
        int* bucket = wsi + 400000;
        unsigned short* meanb = (unsigned short*)(wsi + 2000000);
        int2* stage = (int2*)(wsi + 5200000);

        // zero cnt, cursor, offs, parts, bin_cursor in one shot
        hipMemsetAsync(d_ws, 0, 300256 * sizeof(int), stream);

        sage_hist<<<(N_EDGES + 255) / 256, 256, 0, stream>>>(ei, cnt);
        sage_scan_blocks<<<NBLK_SCAN, 256, 0, stream>>>(cnt, offs, parts);
        sage_scan_parts<<<1, 128, 0, stream>>>(parts);
        sage_stage<<<(N_EDGES + EPB - 1) / EPB, 256, 0, stream>>>(ei, parts, bin_cursor, stage);
        sage_bucket<<<NBLK_SCAN, 256, 0, stream>>>(stage, parts, offs, bucket);
        sage_cvt_w<<<(HID_CH * HID_CH + 255) / 256, 256, 0, stream>>>(Wl, Wr, Bt);
        sage_gather_mean<<<(N_NODES + 3) / 4, 256, 0, stream>>>(cnt, offs, parts, bucket, h, meanb);
        sage_mfma<<<(N_NODES / 16 + 3) / 4, 256, 0, stream>>>(meanb, h, Bt, b, out);
    } else {
        // fallback: atomic scatter path
        float* agg = (float*)d_ws;
        float* deg = agg + (size_t)N_NODES * IN_CH;
        hipMemsetAsync(d_ws, 0, ((size_t)N_NODES * IN_CH + N_NODES) * sizeof(float), stream);
        sage_scatter<<<(int)(((long long)N_EDGES * 64 + 255) / 256), 256, 0, stream>>>(ei, h, agg, deg);
        sage_node<<<4096, 128, 0, stream>>>(h, agg, deg, Wl, b, Wr, out);
    }
}

// Round 9
// 189.948 us; speedup vs baseline: 2.6977x; 1.2109x over previous
//
#include <hip/hip_runtime.h>

#define N_NODES 100000
#define N_EDGES 1600000
#define IN_CH 64
#define HID_CH 128

#define BIN_SZ 1024                                    // nodes per bin
#define NBINS ((N_NODES + BIN_SZ - 1) / BIN_SZ)        // 98 bins
#define EPB 2048                                       // edges per stage block

typedef __attribute__((ext_vector_type(8))) short bf16x8;  // 8 bf16 = 4 VGPR
typedef __attribute__((ext_vector_type(4))) float f32x4;

static __device__ __forceinline__ unsigned short f2bf(float f) {
    union { float f; unsigned int u; } v; v.f = f;
    const unsigned int u = v.u;
    return (unsigned short)((u + 0x7FFFu + ((u >> 16) & 1u)) >> 16);  // RNE
}

// ---------------- bin histogram (98 bins, LDS-aggregated) ----------------

__global__ __launch_bounds__(256) void sage_binhist(
    const int* __restrict__ ei, int* __restrict__ bin_tot)
{
    __shared__ int s_bins[NBINS];
    const int t = threadIdx.x;
    const int e0 = blockIdx.x * EPB;
    for (int i = t; i < NBINS; i += 256) s_bins[i] = 0;
    __syncthreads();
#pragma unroll
    for (int k = 0; k < 8; ++k) {
        const int e = e0 + k * 256 + t;
        if (e < N_EDGES) atomicAdd(&s_bins[ei[e] >> 10], 1);
    }
    __syncthreads();
    for (int i = t; i < NBINS; i += 256) {
        const int c = s_bins[i];
        if (c > 0) atomicAdd(&bin_tot[i], c);
    }
}

// Exclusive scan of the 98 bin totals -> bin base offsets.
__global__ __launch_bounds__(128) void sage_scan_parts2(
    const int* __restrict__ bin_tot, int* __restrict__ parts)
{
    __shared__ int s[128];
    const int t = threadIdx.x;
    s[t] = (t < NBINS) ? bin_tot[t] : 0;
    __syncthreads();
    for (int off = 1; off < 128; off <<= 1) {
        int x = s[t];
        if (t >= off) x += s[t - off];
        __syncthreads();
        s[t] = x;
        __syncthreads();
    }
    if (t < NBINS) parts[t] = (t > 0) ? s[t - 1] : 0;
}

// Partition edges into 98 bin regions of `stage` as (dst,src) pairs.
// LDS bin histogram -> one global atomic per bin per block reserves a
// contiguous run -> writes are single-writer runs (near-full-line).
__global__ __launch_bounds__(256) void sage_stage(
    const int* __restrict__ ei, const int* __restrict__ parts,
    int* __restrict__ bin_cursor, int2* __restrict__ stage)
{
    __shared__ int s_cnt[NBINS];
    __shared__ int s_base[NBINS];
    const int t = threadIdx.x;
    const int e0 = blockIdx.x * EPB;
    for (int i = t; i < NBINS; i += 256) s_cnt[i] = 0;
    __syncthreads();
    int dst[8], src[8], bin[8];
#pragma unroll
    for (int k = 0; k < 8; ++k) {
        const int e = e0 + k * 256 + t;
        if (e < N_EDGES) {
            dst[k] = ei[e];
            src[k] = ei[N_EDGES + e];
            bin[k] = dst[k] >> 10;
            atomicAdd(&s_cnt[bin[k]], 1);
        } else bin[k] = -1;
    }
    __syncthreads();
    for (int i = t; i < NBINS; i += 256) {
        const int c = s_cnt[i];
        s_base[i] = (c > 0) ? (parts[i] + atomicAdd(&bin_cursor[i], c)) : 0;
        s_cnt[i] = 0;
    }
    __syncthreads();
#pragma unroll
    for (int k = 0; k < 8; ++k) {
        if (bin[k] >= 0) {
            const int p = s_base[bin[k]] + atomicAdd(&s_cnt[bin[k]], 1);
            stage[p] = make_int2(dst[k], src[k]);
        }
    }
}

// One block per bin: count per-node in LDS, scan 1024 entries in LDS, write
// node_cnt/node_start coalesced, then scatter staged pairs to CSR order.
// All bucket writes land in the bin's ~65KB window (full-line writebacks).
__global__ __launch_bounds__(256) void sage_bucket2(
    const int2* __restrict__ stage, const int* __restrict__ parts,
    int* __restrict__ node_cnt, int* __restrict__ node_start,
    int* __restrict__ bucket)
{
    __shared__ int s_cnt[BIN_SZ];
    __shared__ int s_off[BIN_SZ];
    __shared__ int s_cur[BIN_SZ];
    __shared__ int s_part[256];
    const int b = blockIdx.x;
    const int t = threadIdx.x;
    for (int i = t; i < BIN_SZ; i += 256) { s_cnt[i] = 0; s_cur[i] = 0; }
    __syncthreads();
    const int start = parts[b];
    const int end = (b + 1 < NBINS) ? parts[b + 1] : N_EDGES;
    for (int i = start + t; i < end; i += 256)
        atomicAdd(&s_cnt[stage[i].x & (BIN_SZ - 1)], 1);
    __syncthreads();
    // scan: thread t handles elems [4t, 4t+4)
    const int v0 = s_cnt[4 * t], v1 = s_cnt[4 * t + 1];
    const int v2 = s_cnt[4 * t + 2], v3 = s_cnt[4 * t + 3];
    s_part[t] = v0 + v1 + v2 + v3;
    __syncthreads();
    for (int off = 1; off < 256; off <<= 1) {
        int x = s_part[t];
        if (t >= off) x += s_part[t - off];
        __syncthreads();
        s_part[t] = x;
        __syncthreads();
    }
    const int excl = (t > 0) ? s_part[t - 1] : 0;
    s_off[4 * t] = excl;
    s_off[4 * t + 1] = excl + v0;
    s_off[4 * t + 2] = excl + v0 + v1;
    s_off[4 * t + 3] = excl + v0 + v1 + v2;
    __syncthreads();
    // coalesced CSR metadata writes
    const int nbase = b << 10;
    for (int i = t; i < BIN_SZ; i += 256) {
        const int node = nbase + i;
        if (node < N_NODES) {
            node_cnt[node] = s_cnt[i];
            node_start[node] = start + s_off[i];
        }
    }
    // scatter pass
    for (int i = start + t; i < end; i += 256) {
        const int2 p = stage[i];
        const int l = p.x & (BIN_SZ - 1);
        bucket[start + s_off[l] + atomicAdd(&s_cur[l], 1)] = p.y;
    }
}

// ---------------- bf16 weight pack ----------------
// Bt[n][k] = bf16( k<64 ? Wl[k][n] : Wr[k-64][n] )  -- [128][128]
__global__ __launch_bounds__(256) void sage_cvt_w(
    const float* __restrict__ Wl, const float* __restrict__ Wr,
    unsigned short* __restrict__ Bt)
{
    const int i = blockIdx.x * blockDim.x + threadIdx.x;
    if (i >= HID_CH * HID_CH) return;
    const int n = i >> 7, k = i & 127;
    const float v = (k < 64) ? Wl[k * HID_CH + n] : Wr[(k - 64) * HID_CH + n];
    Bt[i] = f2bf(v);
}

// ---------------- gather + mean (writes bf16) ----------------
// One 64-lane wave per node; 16 lanes x float4 cover one 256B row, so the
// wave processes 4 edges concurrently (4 independent gathers in flight).
__global__ __launch_bounds__(256) void sage_gather_mean(
    const int* __restrict__ node_cnt, const int* __restrict__ node_start,
    const int* __restrict__ bucket, const float* __restrict__ h,
    unsigned short* __restrict__ meanb)
{
    const int node = blockIdx.x * 4 + (threadIdx.x >> 6);
    const int lane = threadIdx.x & 63;
    const int sub = lane >> 4;        // edge slot 0..3
    const int c4 = lane & 15;         // float4 index within the 64-ch row
    if (node >= N_NODES) return;
    const int d = node_cnt[node];
    const int start = node_start[node];

    float4 acc = make_float4(0.f, 0.f, 0.f, 0.f);
    int i = 0;
#pragma unroll 2
    for (; i + 4 <= d; i += 4) {
        const int s = bucket[start + i + sub];
        const float4 v = *reinterpret_cast<const float4*>(h + (size_t)s * IN_CH + c4 * 4);
        acc.x += v.x; acc.y += v.y; acc.z += v.z; acc.w += v.w;
    }
    if (i + sub < d) {
        const int s = bucket[start + i + sub];
        const float4 v = *reinterpret_cast<const float4*>(h + (size_t)s * IN_CH + c4 * 4);
        acc.x += v.x; acc.y += v.y; acc.z += v.z; acc.w += v.w;
    }
    acc.x += __shfl_xor(acc.x, 16); acc.y += __shfl_xor(acc.y, 16);
    acc.z += __shfl_xor(acc.z, 16); acc.w += __shfl_xor(acc.w, 16);
    acc.x += __shfl_xor(acc.x, 32); acc.y += __shfl_xor(acc.y, 32);
    acc.z += __shfl_xor(acc.z, 32); acc.w += __shfl_xor(acc.w, 32);

    if (sub == 0) {
        const float inv = 1.0f / (float)((d > 1) ? d : 1);
        ushort4 r;
        r.x = f2bf(acc.x * inv); r.y = f2bf(acc.y * inv);
        r.z = f2bf(acc.z * inv); r.w = f2bf(acc.w * inv);
        reinterpret_cast<ushort4*>(meanb + (size_t)node * IN_CH)[c4] = r;
    }
}

// ---------------- MFMA epilogue ----------------
// out[100000 x 128] = concat(meanb, bf16(h)) @ Bt^T + bias, fp32 accumulate.
// One wave per 16-node tile; 8 col-tiles x 4 k-tiles = 32 MFMA per wave.
// h is read fp32 and converted in-register.
__global__ __launch_bounds__(256) void sage_mfma(
    const unsigned short* __restrict__ meanb, const float* __restrict__ h,
    const unsigned short* __restrict__ Bt, const float* __restrict__ bias,
    float* __restrict__ out)
{
    const int wid = (blockIdx.x * blockDim.x + threadIdx.x) >> 6;  // m-tile
    if (wid >= N_NODES / 16) return;
    const int lane = threadIdx.x & 63;
    const int lrow = lane & 15;
    const int lk8 = (lane >> 4) * 8;
    const int node0 = wid * 16;

    bf16x8 a[4];
    {
        const unsigned short* am = meanb + (size_t)(node0 + lrow) * IN_CH;
        a[0] = *reinterpret_cast<const bf16x8*>(am + lk8);
        a[1] = *reinterpret_cast<const bf16x8*>(am + 32 + lk8);
        const float* ah = h + (size_t)(node0 + lrow) * IN_CH;
        const float4 f0 = *reinterpret_cast<const float4*>(ah + lk8);
        const float4 f1 = *reinterpret_cast<const float4*>(ah + lk8 + 4);
        const float4 f2 = *reinterpret_cast<const float4*>(ah + 32 + lk8);
        const float4 f3 = *reinterpret_cast<const float4*>(ah + 32 + lk8 + 4);
        bf16x8 a2, a3;
        a2[0] = (short)f2bf(f0.x); a2[1] = (short)f2bf(f0.y);
        a2[2] = (short)f2bf(f0.z); a2[3] = (short)f2bf(f0.w);
        a2[4] = (short)f2bf(f1.x); a2[5] = (short)f2bf(f1.y);
        a2[6] = (short)f2bf(f1.z); a2[7] = (short)f2bf(f1.w);
        a3[0] = (short)f2bf(f2.x); a3[1] = (short)f2bf(f2.y);
        a3[2] = (short)f2bf(f2.z); a3[3] = (short)f2bf(f2.w);
        a3[4] = (short)f2bf(f3.x); a3[5] = (short)f2bf(f3.y);
        a3[6] = (short)f2bf(f3.z); a3[7] = (short)f2bf(f3.w);
        a[2] = a2; a[3] = a3;
    }

    f32x4 acc[8];
#pragma unroll
    for (int ct = 0; ct < 8; ++ct) {
        acc[ct] = (f32x4){0.f, 0.f, 0.f, 0.f};
#pragma unroll
        for (int kk = 0; kk < 4; ++kk) {
            const bf16x8 b = *reinterpret_cast<const bf16x8*>(
                Bt + (size_t)(ct * 16 + lrow) * 128 + kk * 32 + lk8);
            acc[ct] = __builtin_amdgcn_mfma_f32_16x16x32_bf16(a[kk], b, acc[ct], 0, 0, 0);
        }
    }

#pragma unroll
    for (int ct = 0; ct < 8; ++ct) {
        const int ch = ct * 16 + lrow;
        const float bv = bias[ch];
#pragma unroll
        for (int r = 0; r < 4; ++r) {
            const int node = node0 + (lane >> 4) * 4 + r;
            out[(size_t)node * HID_CH + ch] = acc[ct][r] + bv;
        }
    }
}

// ---------------- fallback (old atomic path) ----------------

__global__ __launch_bounds__(256) void sage_scatter(
    const int* __restrict__ ei, const float* __restrict__ h,
    float* __restrict__ agg, float* __restrict__ deg)
{
    const int gtid = blockIdx.x * blockDim.x + threadIdx.x;
    const int edge = gtid >> 6;
    const int lane = threadIdx.x & 63;
    if (edge >= N_EDGES) return;
    const int dst = ei[edge];
    const int src = ei[N_EDGES + edge];
    atomicAdd(&agg[(size_t)dst * IN_CH + lane], h[(size_t)src * IN_CH + lane]);
    if (lane == 0) atomicAdd(&deg[dst], 1.0f);
}

__global__ __launch_bounds__(128) void sage_node(
    const float* __restrict__ h, const float* __restrict__ agg,
    const float* __restrict__ deg, const float* __restrict__ Wl,
    const float* __restrict__ bias, const float* __restrict__ Wr,
    float* __restrict__ out)
{
    const int t = threadIdx.x;
    float wl[IN_CH], wr[IN_CH];
#pragma unroll
    for (int k = 0; k < IN_CH; ++k) {
        wl[k] = Wl[k * HID_CH + t];
        wr[k] = Wr[k * HID_CH + t];
    }
    const float b = bias[t];
    __shared__ float s_mean[IN_CH];
    __shared__ float s_h[IN_CH];
    for (int n = blockIdx.x; n < N_NODES; n += gridDim.x) {
        __syncthreads();
        if (t < IN_CH) {
            const float inv = 1.0f / fmaxf(deg[n], 1.0f);
            s_mean[t] = agg[(size_t)n * IN_CH + t] * inv;
            s_h[t] = h[(size_t)n * IN_CH + t];
        }
        __syncthreads();
        float acc = b;
#pragma unroll
        for (int k = 0; k < IN_CH; ++k) {
            acc = fmaf(s_mean[k], wl[k], acc);
            acc = fmaf(s_h[k], wr[k], acc);
        }
        out[(size_t)n * HID_CH + t] = acc;
    }
}

extern "C" void kernel_launch(void* const* d_in, const int* in_sizes, int n_in,
                              void* d_out, int out_size, void* d_ws, size_t ws_size,
                              hipStream_t stream) {
    // inputs: 0=x (unused), 1=edge_index, 2=emb_weight, 3=lin_l_w, 4=lin_l_b, 5=lin_r_w
    const int* ei = (const int*)d_in[1];
    const float* h = (const float*)d_in[2];
    const float* Wl = (const float*)d_in[3];
    const float* b = (const float*)d_in[4];
    const float* Wr = (const float*)d_in[5];
    float* out = (float*)d_out;

    // ws layout (4B elements):
    //   node_cnt   [0,       100000)
    //   node_start [100000,  200000)
    //   bin_tot    [300000,  300128)   (zeroed)
    //   bin_cursor [300128,  300256)   (zeroed)
    //   parts      [300256,  300384)
    //   Bt         [300400,  308592)   (bf16 128x128 = 8192 dwords)
    //   bucket     [400000, 2000000)
    //   meanb      [2000000, 5200000)  (bf16 100000x64 = 3.2M dwords)
    //   stage      [5200000, 8400000)  (int2 x 1.6M = 3.2M dwords)
    const size_t need = 8400000ull * 4ull;

    if (ws_size >= need) {
        int* wsi = (int*)d_ws;
        int* node_cnt = wsi;
        int* node_start = wsi + 100000;
        int* bin_tot = wsi + 300000;
        int* bin_cursor = wsi + 300128;
        int* parts = wsi + 300256;
        unsigned short* Bt = (unsigned short*)(wsi + 300400);
        int* bucket = wsi + 400000;
        unsigned short* meanb = (unsigned short*)(wsi + 2000000);
        int2* stage = (int2*)(wsi + 5200000);

        hipMemsetAsync(bin_tot, 0, 256 * sizeof(int), stream);  // bin_tot + bin_cursor

        sage_binhist<<<(N_EDGES + EPB - 1) / EPB, 256, 0, stream>>>(ei, bin_tot);
        sage_scan_parts2<<<1, 128, 0, stream>>>(bin_tot, parts);
        sage_stage<<<(N_EDGES + EPB - 1) / EPB, 256, 0, stream>>>(ei, parts, bin_cursor, stage);
        sage_bucket2<<<NBINS, 256, 0, stream>>>(stage, parts, node_cnt, node_start, bucket);
        sage_cvt_w<<<(HID_CH * HID_CH + 255) / 256, 256, 0, stream>>>(Wl, Wr, Bt);
        sage_gather_mean<<<(N_NODES + 3) / 4, 256, 0, stream>>>(node_cnt, node_start, bucket, h, meanb);
        sage_mfma<<<(N_NODES / 16 + 3) / 4, 256, 0, stream>>>(meanb, h, Bt, b, out);
    } else {
        // fallback: atomic scatter path
        float* agg = (float*)d_ws;
        float* deg = agg + (size_t)N_NODES * IN_CH;
        hipMemsetAsync(d_ws, 0, ((size_t)N_NODES * IN_CH + N_NODES) * sizeof(float), stream);
        sage_scatter<<<(int)(((long long)N_EDGES * 64 + 255) / 256), 256, 0, stream>>>(ei, h, agg, deg);
        sage_node<<<4096, 128, 0, stream>>>(h, agg, deg, Wl, b, Wr, out);
    }
}

// Round 10
// 177.086 us; speedup vs baseline: 2.8936x; 1.0726x over previous
//
#include <hip/hip_runtime.h>

#define N_NODES 100000
#define N_EDGES 1600000
#define IN_CH 64
#define HID_CH 128

#define BIN_SZ 1024                                    // nodes per bin
#define NBINS ((N_NODES + BIN_SZ - 1) / BIN_SZ)        // 98 bins
#define EPB 2048                                       // edges per stage block

typedef __attribute__((ext_vector_type(8))) short bf16x8;  // 8 bf16 = 4 VGPR
typedef __attribute__((ext_vector_type(4))) float f32x4;

static __device__ __forceinline__ unsigned short f2bf(float f) {
    union { float f; unsigned int u; } v; v.f = f;
    const unsigned int u = v.u;
    return (unsigned short)((u + 0x7FFFu + ((u >> 16) & 1u)) >> 16);  // RNE
}

// ---------------- bin histogram (98 bins, LDS-aggregated) ----------------

__global__ __launch_bounds__(256) void sage_binhist(
    const int* __restrict__ ei, int* __restrict__ bin_tot)
{
    __shared__ int s_bins[NBINS];
    const int t = threadIdx.x;
    const int e0 = blockIdx.x * EPB;
    for (int i = t; i < NBINS; i += 256) s_bins[i] = 0;
    __syncthreads();
#pragma unroll
    for (int k = 0; k < 8; ++k) {
        const int e = e0 + k * 256 + t;
        if (e < N_EDGES) atomicAdd(&s_bins[ei[e] >> 10], 1);
    }
    __syncthreads();
    for (int i = t; i < NBINS; i += 256) {
        const int c = s_bins[i];
        if (c > 0) atomicAdd(&bin_tot[i], c);
    }
}

// Exclusive scan of the 98 bin totals -> bin base offsets.
__global__ __launch_bounds__(128) void sage_scan_parts2(
    const int* __restrict__ bin_tot, int* __restrict__ parts)
{
    __shared__ int s[128];
    const int t = threadIdx.x;
    s[t] = (t < NBINS) ? bin_tot[t] : 0;
    __syncthreads();
    for (int off = 1; off < 128; off <<= 1) {
        int x = s[t];
        if (t >= off) x += s[t - off];
        __syncthreads();
        s[t] = x;
        __syncthreads();
    }
    if (t < NBINS) parts[t] = (t > 0) ? s[t - 1] : 0;
}

// Partition edges into 98 bin regions of `stage`, packed as
// ((dst&1023)<<17) | src  (src < 2^17). One int per edge.
__global__ __launch_bounds__(256) void sage_stage(
    const int* __restrict__ ei, const int* __restrict__ parts,
    int* __restrict__ bin_cursor, int* __restrict__ stage)
{
    __shared__ int s_cnt[NBINS];
    __shared__ int s_base[NBINS];
    const int t = threadIdx.x;
    const int e0 = blockIdx.x * EPB;
    for (int i = t; i < NBINS; i += 256) s_cnt[i] = 0;
    __syncthreads();
    int pk[8], bin[8];
#pragma unroll
    for (int k = 0; k < 8; ++k) {
        const int e = e0 + k * 256 + t;
        if (e < N_EDGES) {
            const int dst = ei[e];
            const int src = ei[N_EDGES + e];
            bin[k] = dst >> 10;
            pk[k] = ((dst & (BIN_SZ - 1)) << 17) | src;
            atomicAdd(&s_cnt[bin[k]], 1);
        } else bin[k] = -1;
    }
    __syncthreads();
    for (int i = t; i < NBINS; i += 256) {
        const int c = s_cnt[i];
        s_base[i] = (c > 0) ? (parts[i] + atomicAdd(&bin_cursor[i], c)) : 0;
        s_cnt[i] = 0;
    }
    __syncthreads();
#pragma unroll
    for (int k = 0; k < 8; ++k) {
        if (bin[k] >= 0) {
            const int p = s_base[bin[k]] + atomicAdd(&s_cnt[bin[k]], 1);
            stage[p] = pk[k];
        }
    }
}

// One block per bin: count per-node in LDS, scan 1024 entries in LDS, write
// node_cnt/node_start coalesced, then scatter staged srcs to CSR order.
__global__ __launch_bounds__(256) void sage_bucket2(
    const int* __restrict__ stage, const int* __restrict__ parts,
    int* __restrict__ node_cnt, int* __restrict__ node_start,
    int* __restrict__ bucket)
{
    __shared__ int s_cnt[BIN_SZ];
    __shared__ int s_off[BIN_SZ];
    __shared__ int s_cur[BIN_SZ];
    __shared__ int s_part[256];
    const int b = blockIdx.x;
    const int t = threadIdx.x;
    for (int i = t; i < BIN_SZ; i += 256) { s_cnt[i] = 0; s_cur[i] = 0; }
    __syncthreads();
    const int start = parts[b];
    const int end = (b + 1 < NBINS) ? parts[b + 1] : N_EDGES;
    for (int i = start + t; i < end; i += 256)
        atomicAdd(&s_cnt[stage[i] >> 17], 1);
    __syncthreads();
    // scan: thread t handles elems [4t, 4t+4)
    const int v0 = s_cnt[4 * t], v1 = s_cnt[4 * t + 1];
    const int v2 = s_cnt[4 * t + 2], v3 = s_cnt[4 * t + 3];
    s_part[t] = v0 + v1 + v2 + v3;
    __syncthreads();
    for (int off = 1; off < 256; off <<= 1) {
        int x = s_part[t];
        if (t >= off) x += s_part[t - off];
        __syncthreads();
        s_part[t] = x;
        __syncthreads();
    }
    const int excl = (t > 0) ? s_part[t - 1] : 0;
    s_off[4 * t] = excl;
    s_off[4 * t + 1] = excl + v0;
    s_off[4 * t + 2] = excl + v0 + v1;
    s_off[4 * t + 3] = excl + v0 + v1 + v2;
    __syncthreads();
    // coalesced CSR metadata writes
    const int nbase = b << 10;
    for (int i = t; i < BIN_SZ; i += 256) {
        const int node = nbase + i;
        if (node < N_NODES) {
            node_cnt[node] = s_cnt[i];
            node_start[node] = start + s_off[i];
        }
    }
    // scatter pass
    for (int i = start + t; i < end; i += 256) {
        const int p = stage[i];
        const int l = p >> 17;
        bucket[start + s_off[l] + atomicAdd(&s_cur[l], 1)] = p & 0x1FFFF;
    }
}

// ---------------- bf16 conversions ----------------

__global__ __launch_bounds__(256) void sage_cvt_h(
    const float* __restrict__ h, unsigned short* __restrict__ hb)
{
    const int n4 = N_NODES * IN_CH / 4;
    for (int i = blockIdx.x * blockDim.x + threadIdx.x; i < n4;
         i += gridDim.x * blockDim.x) {
        const float4 v = reinterpret_cast<const float4*>(h)[i];
        ushort4 o;
        o.x = f2bf(v.x); o.y = f2bf(v.y); o.z = f2bf(v.z); o.w = f2bf(v.w);
        reinterpret_cast<ushort4*>(hb)[i] = o;
    }
}

// Bt[n][k] = bf16( k<64 ? Wl[k][n] : Wr[k-64][n] )  -- [128][128]
__global__ __launch_bounds__(256) void sage_cvt_w(
    const float* __restrict__ Wl, const float* __restrict__ Wr,
    unsigned short* __restrict__ Bt)
{
    const int i = blockIdx.x * blockDim.x + threadIdx.x;
    if (i >= HID_CH * HID_CH) return;
    const int n = i >> 7, k = i & 127;
    const float v = (k < 64) ? Wl[k * HID_CH + n] : Wr[(k - 64) * HID_CH + n];
    Bt[i] = f2bf(v);
}

// ---------------- gather + mean (bf16 rows, 8 edges/wave) ----------------
// 8 lanes x 16B (bf16x8) cover one 128B bf16 row; wave processes 8 edges
// concurrently. bf16->fp32 is <<16 / &0xFFFF0000 bit-ops, fp32 accumulate.
__global__ __launch_bounds__(256) void sage_gather_mean(
    const int* __restrict__ node_cnt, const int* __restrict__ node_start,
    const int* __restrict__ bucket, const unsigned short* __restrict__ hb,
    unsigned short* __restrict__ meanb)
{
    const int node = blockIdx.x * 4 + (threadIdx.x >> 6);
    const int lane = threadIdx.x & 63;
    const int sub = lane >> 3;        // edge slot 0..7
    const int c8 = lane & 7;          // 8-channel group within the row
    if (node >= N_NODES) return;
    const int d = node_cnt[node];
    const int start = node_start[node];

    float acc[8] = {0.f, 0.f, 0.f, 0.f, 0.f, 0.f, 0.f, 0.f};
    int i = 0;
    for (; i + 8 <= d; i += 8) {
        const int s = bucket[start + i + sub];
        const uint4 v = *reinterpret_cast<const uint4*>(hb + (size_t)s * IN_CH + c8 * 8);
        union { unsigned int u; float f; } lo, hi;
#pragma unroll
        for (int j = 0; j < 4; ++j) {
            const unsigned int w = (&v.x)[j];
            lo.u = w << 16;        acc[2 * j] += lo.f;
            hi.u = w & 0xFFFF0000u; acc[2 * j + 1] += hi.f;
        }
    }
    if (i + sub < d) {
        const int s = bucket[start + i + sub];
        const uint4 v = *reinterpret_cast<const uint4*>(hb + (size_t)s * IN_CH + c8 * 8);
        union { unsigned int u; float f; } lo, hi;
#pragma unroll
        for (int j = 0; j < 4; ++j) {
            const unsigned int w = (&v.x)[j];
            lo.u = w << 16;        acc[2 * j] += lo.f;
            hi.u = w & 0xFFFF0000u; acc[2 * j + 1] += hi.f;
        }
    }
    // reduce the 8 edge slots (lanes ^8, ^16, ^32)
#pragma unroll
    for (int j = 0; j < 8; ++j) {
        acc[j] += __shfl_xor(acc[j], 8);
        acc[j] += __shfl_xor(acc[j], 16);
        acc[j] += __shfl_xor(acc[j], 32);
    }

    if (sub == 0) {
        const float inv = 1.0f / (float)((d > 1) ? d : 1);
        uint4 o;
#pragma unroll
        for (int j = 0; j < 4; ++j) {
            const unsigned int l = f2bf(acc[2 * j] * inv);
            const unsigned int hgh = f2bf(acc[2 * j + 1] * inv);
            (&o.x)[j] = l | (hgh << 16);
        }
        *reinterpret_cast<uint4*>(meanb + (size_t)node * IN_CH + c8 * 8) = o;
    }
}

// ---------------- MFMA epilogue ----------------
// out[100000 x 128] = concat(meanb, hb) @ Bt^T + bias, fp32 accumulate.
// One wave per 16-node tile; 8 col-tiles x 4 k-tiles = 32 MFMA per wave.
__global__ __launch_bounds__(256) void sage_mfma(
    const unsigned short* __restrict__ meanb, const unsigned short* __restrict__ hb,
    const unsigned short* __restrict__ Bt, const float* __restrict__ bias,
    float* __restrict__ out)
{
    const int wid = (blockIdx.x * blockDim.x + threadIdx.x) >> 6;  // m-tile
    if (wid >= N_NODES / 16) return;
    const int lane = threadIdx.x & 63;
    const int lrow = lane & 15;
    const int lk8 = (lane >> 4) * 8;
    const int node0 = wid * 16;

    bf16x8 a[4];
    {
        const unsigned short* am = meanb + (size_t)(node0 + lrow) * IN_CH;
        const unsigned short* ah = hb + (size_t)(node0 + lrow) * IN_CH;
        a[0] = *reinterpret_cast<const bf16x8*>(am + lk8);
        a[1] = *reinterpret_cast<const bf16x8*>(am + 32 + lk8);
        a[2] = *reinterpret_cast<const bf16x8*>(ah + lk8);
        a[3] = *reinterpret_cast<const bf16x8*>(ah + 32 + lk8);
    }

    f32x4 acc[8];
#pragma unroll
    for (int ct = 0; ct < 8; ++ct) {
        acc[ct] = (f32x4){0.f, 0.f, 0.f, 0.f};
#pragma unroll
        for (int kk = 0; kk < 4; ++kk) {
            const bf16x8 b = *reinterpret_cast<const bf16x8*>(
                Bt + (size_t)(ct * 16 + lrow) * 128 + kk * 32 + lk8);
            acc[ct] = __builtin_amdgcn_mfma_f32_16x16x32_bf16(a[kk], b, acc[ct], 0, 0, 0);
        }
    }

#pragma unroll
    for (int ct = 0; ct < 8; ++ct) {
        const int ch = ct * 16 + lrow;
        const float bv = bias[ch];
#pragma unroll
        for (int r = 0; r < 4; ++r) {
            const int node = node0 + (lane >> 4) * 4 + r;
            out[(size_t)node * HID_CH + ch] = acc[ct][r] + bv;
        }
    }
}

// ---------------- fallback (old atomic path) ----------------

__global__ __launch_bounds__(256) void sage_scatter(
    const int* __restrict__ ei, const float* __restrict__ h,
    float* __restrict__ agg, float* __restrict__ deg)
{
    const int gtid = blockIdx.x * blockDim.x + threadIdx.x;
    const int edge = gtid >> 6;
    const int lane = threadIdx.x & 63;
    if (edge >= N_EDGES) return;
    const int dst = ei[edge];
    const int src = ei[N_EDGES + edge];
    atomicAdd(&agg[(size_t)dst * IN_CH + lane], h[(size_t)src * IN_CH + lane]);
    if (lane == 0) atomicAdd(&deg[dst], 1.0f);
}

__global__ __launch_bounds__(128) void sage_node(
    const float* __restrict__ h, const float* __restrict__ agg,
    const float* __restrict__ deg, const float* __restrict__ Wl,
    const float* __restrict__ bias, const float* __restrict__ Wr,
    float* __restrict__ out)
{
    const int t = threadIdx.x;
    float wl[IN_CH], wr[IN_CH];
#pragma unroll
    for (int k = 0; k < IN_CH; ++k) {
        wl[k] = Wl[k * HID_CH + t];
        wr[k] = Wr[k * HID_CH + t];
    }
    const float b = bias[t];
    __shared__ float s_mean[IN_CH];
    __shared__ float s_h[IN_CH];
    for (int n = blockIdx.x; n < N_NODES; n += gridDim.x) {
        __syncthreads();
        if (t < IN_CH) {
            const float inv = 1.0f / fmaxf(deg[n], 1.0f);
            s_mean[t] = agg[(size_t)n * IN_CH + t] * inv;
            s_h[t] = h[(size_t)n * IN_CH + t];
        }
        __syncthreads();
        float acc = b;
#pragma unroll
        for (int k = 0; k < IN_CH; ++k) {
            acc = fmaf(s_mean[k], wl[k], acc);
            acc = fmaf(s_h[k], wr[k], acc);
        }
        out[(size_t)n * HID_CH + t] = acc;
    }
}

extern "C" void kernel_launch(void* const* d_in, const int* in_sizes, int n_in,
                              void* d_out, int out_size, void* d_ws, size_t ws_size,
                              hipStream_t stream) {
    // inputs: 0=x (unused), 1=edge_index, 2=emb_weight, 3=lin_l_w, 4=lin_l_b, 5=lin_r_w
    const int* ei = (const int*)d_in[1];
    const float* h = (const float*)d_in[2];
    const float* Wl = (const float*)d_in[3];
    const float* b = (const float*)d_in[4];
    const float* Wr = (const float*)d_in[5];
    float* out = (float*)d_out;

    // ws layout (4B elements):
    //   node_cnt   [0,       100000)
    //   node_start [100000,  200000)
    //   bin_tot    [300000,  300128)   (zeroed)
    //   bin_cursor [300128,  300256)   (zeroed)
    //   parts      [300256,  300384)
    //   Bt         [300400,  308592)   (bf16 128x128 = 8192 dwords)
    //   bucket     [400000, 2000000)   (1.6M dwords)
    //   meanb      [2000000, 5200000)  (bf16 100000x64 = 3.2M dwords)
    //   stage      [5200000, 6800000)  (packed int x 1.6M) -- consumed by bucket2,
    //   hb         [5200000, 8400000)  then overwritten by cvt_h (same region)
    const size_t need = 8400000ull * 4ull;

    if (ws_size >= need) {
        int* wsi = (int*)d_ws;
        int* node_cnt = wsi;
        int* node_start = wsi + 100000;
        int* bin_tot = wsi + 300000;
        int* bin_cursor = wsi + 300128;
        int* parts = wsi + 300256;
        unsigned short* Bt = (unsigned short*)(wsi + 300400);
        int* bucket = wsi + 400000;
        unsigned short* meanb = (unsigned short*)(wsi + 2000000);
        int* stage = wsi + 5200000;
        unsigned short* hb = (unsigned short*)(wsi + 5200000);

        hipMemsetAsync(bin_tot, 0, 256 * sizeof(int), stream);  // bin_tot + bin_cursor

        sage_binhist<<<(N_EDGES + EPB - 1) / EPB, 256, 0, stream>>>(ei, bin_tot);
        sage_scan_parts2<<<1, 128, 0, stream>>>(bin_tot, parts);
        sage_stage<<<(N_EDGES + EPB - 1) / EPB, 256, 0, stream>>>(ei, parts, bin_cursor, stage);
        sage_bucket2<<<NBINS, 256, 0, stream>>>(stage, parts, node_cnt, node_start, bucket);
        sage_cvt_h<<<1024, 256, 0, stream>>>(h, hb);  // overwrites stage (safe: bucket2 done)
        sage_cvt_w<<<(HID_CH * HID_CH + 255) / 256, 256, 0, stream>>>(Wl, Wr, Bt);
        sage_gather_mean<<<(N_NODES + 3) / 4, 256, 0, stream>>>(node_cnt, node_start, bucket, hb, meanb);
        sage_mfma<<<(N_NODES / 16 + 3) / 4, 256, 0, stream>>>(meanb, hb, Bt, b, out);
    } else {
        // fallback: atomic scatter path
        float* agg = (float*)d_ws;
        float* deg = agg + (size_t)N_NODES * IN_CH;
        hipMemsetAsync(d_ws, 0, ((size_t)N_NODES * IN_CH + N_NODES) * sizeof(float), stream);
        sage_scatter<<<(int)(((long long)N_EDGES * 64 + 255) / 256), 256, 0, stream>>>(ei, h, agg, deg);
        sage_node<<<4096, 128, 0, stream>>>(h, agg, deg, Wl, b, Wr, out);
    }
}

// Round 11
// 168.649 us; speedup vs baseline: 3.0383x; 1.0500x over previous
//
#include <hip/hip_runtime.h>

#define N_NODES 100000
#define N_EDGES 1600000
#define IN_CH 64
#define HID_CH 128

#define BIN_SZ 256                                     // nodes per bin
#define BIN_BITS 8
#define NBINS ((N_NODES + BIN_SZ - 1) / BIN_SZ)        // 391 bins
#define EPB 2048                                       // edges per stage block
#define HIST_BLOCKS ((N_EDGES + EPB - 1) / EPB)        // 782
#define CVTW_BLOCKS ((HID_CH * HID_CH + 255) / 256)    // 64
#define BIN_CACHE 8192                                 // LDS edge cache per bin

typedef __attribute__((ext_vector_type(8))) short bf16x8;  // 8 bf16 = 4 VGPR
typedef __attribute__((ext_vector_type(4))) float f32x4;

static __device__ __forceinline__ unsigned short f2bf(float f) {
    union { float f; unsigned int u; } v; v.f = f;
    const unsigned int u = v.u;
    return (unsigned short)((u + 0x7FFFu + ((u >> 16) & 1u)) >> 16);  // RNE
}

// ---------------- prep: bin histogram + weight pack (fused) ----------------

__global__ __launch_bounds__(256) void sage_prep(
    const int* __restrict__ ei, const float* __restrict__ Wl,
    const float* __restrict__ Wr, int* __restrict__ bin_tot,
    unsigned short* __restrict__ Bt)
{
    const int t = threadIdx.x;
    const int bid = blockIdx.x;
    if (bid < HIST_BLOCKS) {
        __shared__ int s_bins[NBINS];
        for (int i = t; i < NBINS; i += 256) s_bins[i] = 0;
        __syncthreads();
        const int e0 = bid * EPB;
#pragma unroll
        for (int k = 0; k < 8; ++k) {
            const int e = e0 + k * 256 + t;
            if (e < N_EDGES) atomicAdd(&s_bins[ei[e] >> BIN_BITS], 1);
        }
        __syncthreads();
        for (int i = t; i < NBINS; i += 256) {
            const int c = s_bins[i];
            if (c > 0) atomicAdd(&bin_tot[i], c);
        }
    } else {
        // weight pack: Bt[n][k] = bf16( k<64 ? Wl[k][n] : Wr[k-64][n] )
        const int i = (bid - HIST_BLOCKS) * 256 + t;
        if (i < HID_CH * HID_CH) {
            const int n = i >> 7, k = i & 127;
            const float v = (k < 64) ? Wl[k * HID_CH + n] : Wr[(k - 64) * HID_CH + n];
            Bt[i] = f2bf(v);
        }
    }
}

// ---------------- stage: partition edges into 391 bin regions ----------------
// Each block locally scans the 391 bin totals (1.5KB, L2-broadcast) to get bin
// bases; block 0 publishes parts[] for bucket2. Packed record:
// ((dst & 255) << 17) | src   (src < 2^17).
__global__ __launch_bounds__(256) void sage_stage(
    const int* __restrict__ ei, const int* __restrict__ bin_tot,
    int* __restrict__ parts, int* __restrict__ bin_cursor,
    int* __restrict__ stage)
{
    __shared__ int sc[512];
    __shared__ int s_cnt[NBINS];
    __shared__ int s_base[NBINS];
    const int t = threadIdx.x;
    sc[t] = (t < NBINS) ? bin_tot[t] : 0;
    sc[t + 256] = (t + 256 < NBINS) ? bin_tot[t + 256] : 0;
    for (int i = t; i < NBINS; i += 256) s_cnt[i] = 0;
    __syncthreads();
    // inclusive Hillis-Steele over 512 entries, 2 per thread
    for (int off = 1; off < 512; off <<= 1) {
        const int a = (t >= off) ? sc[t - off] : 0;
        const int b = (t + 256 >= off) ? sc[t + 256 - off] : 0;
        __syncthreads();
        sc[t] += a; sc[t + 256] += b;
        __syncthreads();
    }
    if (blockIdx.x == 0) {
        for (int i = t; i < NBINS; i += 256)
            parts[i] = (i > 0) ? sc[i - 1] : 0;
    }
    const int e0 = blockIdx.x * EPB;
    int pk[8], bin[8];
#pragma unroll
    for (int k = 0; k < 8; ++k) {
        const int e = e0 + k * 256 + t;
        if (e < N_EDGES) {
            const int dst = ei[e];
            const int src = ei[N_EDGES + e];
            bin[k] = dst >> BIN_BITS;
            pk[k] = ((dst & (BIN_SZ - 1)) << 17) | src;
            atomicAdd(&s_cnt[bin[k]], 1);
        } else bin[k] = -1;
    }
    __syncthreads();
    for (int i = t; i < NBINS; i += 256) {
        const int c = s_cnt[i];
        const int base = (i > 0) ? sc[i - 1] : 0;
        s_base[i] = (c > 0) ? (base + atomicAdd(&bin_cursor[i], c)) : 0;
        s_cnt[i] = 0;
    }
    __syncthreads();
#pragma unroll
    for (int k = 0; k < 8; ++k) {
        if (bin[k] >= 0) {
            const int p = s_base[bin[k]] + atomicAdd(&s_cnt[bin[k]], 1);
            stage[p] = pk[k];
        }
    }
}

// ---------------- bucket2: per-bin CSR finalize ----------------
// One block per bin (391 blocks): cache staged edges in LDS, count per-node,
// scan 256 entries, write node_cnt/node_start coalesced, scatter to bucket.
__global__ __launch_bounds__(256) void sage_bucket2(
    const int* __restrict__ stage, const int* __restrict__ parts,
    int* __restrict__ node_cnt, int* __restrict__ node_start,
    int* __restrict__ bucket)
{
    __shared__ int s_cnt[BIN_SZ];
    __shared__ int s_off[BIN_SZ];
    __shared__ int s_cur[BIN_SZ];
    __shared__ int s_edges[BIN_CACHE];
    const int b = blockIdx.x;
    const int t = threadIdx.x;
    s_cnt[t] = 0; s_cur[t] = 0;
    __syncthreads();
    const int start = parts[b];
    const int end = (b + 1 < NBINS) ? parts[b + 1] : N_EDGES;
    const int len = end - start;
    const bool cached = (len <= BIN_CACHE);
    if (cached) {
        for (int i = t; i < len; i += 256) {
            const int p = stage[start + i];
            s_edges[i] = p;
            atomicAdd(&s_cnt[p >> 17], 1);
        }
    } else {
        for (int i = t; i < len; i += 256)
            atomicAdd(&s_cnt[stage[start + i] >> 17], 1);
    }
    __syncthreads();
    const int v = s_cnt[t];
    s_off[t] = v;
    __syncthreads();
    for (int off = 1; off < 256; off <<= 1) {
        const int a = (t >= off) ? s_off[t - off] : 0;
        __syncthreads();
        s_off[t] += a;
        __syncthreads();
    }
    const int excl = s_off[t] - v;
    s_off[t] = excl;
    __syncthreads();
    const int node = (b << BIN_BITS) + t;
    if (node < N_NODES) {
        node_cnt[node] = v;
        node_start[node] = start + excl;
    }
    if (cached) {
        for (int i = t; i < len; i += 256) {
            const int p = s_edges[i];
            const int l = p >> 17;
            bucket[start + s_off[l] + atomicAdd(&s_cur[l], 1)] = p & 0x1FFFF;
        }
    } else {
        for (int i = t; i < len; i += 256) {
            const int p = stage[start + i];
            const int l = p >> 17;
            bucket[start + s_off[l] + atomicAdd(&s_cur[l], 1)] = p & 0x1FFFF;
        }
    }
}

// ---------------- bf16 conversion of h (after bucket2; hb aliases stage) ----

__global__ __launch_bounds__(256) void sage_cvt_h(
    const float* __restrict__ h, unsigned short* __restrict__ hb)
{
    const int n4 = N_NODES * IN_CH / 4;
    for (int i = blockIdx.x * blockDim.x + threadIdx.x; i < n4;
         i += gridDim.x * blockDim.x) {
        const float4 v = reinterpret_cast<const float4*>(h)[i];
        ushort4 o;
        o.x = f2bf(v.x); o.y = f2bf(v.y); o.z = f2bf(v.z); o.w = f2bf(v.w);
        reinterpret_cast<ushort4*>(hb)[i] = o;
    }
}

// ---------------- gather + mean (bf16 rows, 8 edges/wave) ----------------

__global__ __launch_bounds__(256) void sage_gather_mean(
    const int* __restrict__ node_cnt, const int* __restrict__ node_start,
    const int* __restrict__ bucket, const unsigned short* __restrict__ hb,
    unsigned short* __restrict__ meanb)
{
    const int node = blockIdx.x * 4 + (threadIdx.x >> 6);
    const int lane = threadIdx.x & 63;
    const int sub = lane >> 3;        // edge slot 0..7
    const int c8 = lane & 7;          // 8-channel group within the row
    if (node >= N_NODES) return;
    const int d = node_cnt[node];
    const int start = node_start[node];

    float acc[8] = {0.f, 0.f, 0.f, 0.f, 0.f, 0.f, 0.f, 0.f};
    int i = 0;
    for (; i + 8 <= d; i += 8) {
        const int s = bucket[start + i + sub];
        const uint4 v = *reinterpret_cast<const uint4*>(hb + (size_t)s * IN_CH + c8 * 8);
        union { unsigned int u; float f; } lo, hi;
#pragma unroll
        for (int j = 0; j < 4; ++j) {
            const unsigned int w = (&v.x)[j];
            lo.u = w << 16;         acc[2 * j] += lo.f;
            hi.u = w & 0xFFFF0000u; acc[2 * j + 1] += hi.f;
        }
    }
    if (i + sub < d) {
        const int s = bucket[start + i + sub];
        const uint4 v = *reinterpret_cast<const uint4*>(hb + (size_t)s * IN_CH + c8 * 8);
        union { unsigned int u; float f; } lo, hi;
#pragma unroll
        for (int j = 0; j < 4; ++j) {
            const unsigned int w = (&v.x)[j];
            lo.u = w << 16;         acc[2 * j] += lo.f;
            hi.u = w & 0xFFFF0000u; acc[2 * j + 1] += hi.f;
        }
    }
#pragma unroll
    for (int j = 0; j < 8; ++j) {
        acc[j] += __shfl_xor(acc[j], 8);
        acc[j] += __shfl_xor(acc[j], 16);
        acc[j] += __shfl_xor(acc[j], 32);
    }

    if (sub == 0) {
        const float inv = 1.0f / (float)((d > 1) ? d : 1);
        uint4 o;
#pragma unroll
        for (int j = 0; j < 4; ++j) {
            const unsigned int l = f2bf(acc[2 * j] * inv);
            const unsigned int hgh = f2bf(acc[2 * j + 1] * inv);
            (&o.x)[j] = l | (hgh << 16);
        }
        *reinterpret_cast<uint4*>(meanb + (size_t)node * IN_CH + c8 * 8) = o;
    }
}

// ---------------- MFMA epilogue ----------------

__global__ __launch_bounds__(256) void sage_mfma(
    const unsigned short* __restrict__ meanb, const unsigned short* __restrict__ hb,
    const unsigned short* __restrict__ Bt, const float* __restrict__ bias,
    float* __restrict__ out)
{
    const int wid = (blockIdx.x * blockDim.x + threadIdx.x) >> 6;  // m-tile
    if (wid >= N_NODES / 16) return;
    const int lane = threadIdx.x & 63;
    const int lrow = lane & 15;
    const int lk8 = (lane >> 4) * 8;
    const int node0 = wid * 16;

    bf16x8 a[4];
    {
        const unsigned short* am = meanb + (size_t)(node0 + lrow) * IN_CH;
        const unsigned short* ah = hb + (size_t)(node0 + lrow) * IN_CH;
        a[0] = *reinterpret_cast<const bf16x8*>(am + lk8);
        a[1] = *reinterpret_cast<const bf16x8*>(am + 32 + lk8);
        a[2] = *reinterpret_cast<const bf16x8*>(ah + lk8);
        a[3] = *reinterpret_cast<const bf16x8*>(ah + 32 + lk8);
    }

    f32x4 acc[8];
#pragma unroll
    for (int ct = 0; ct < 8; ++ct) {
        acc[ct] = (f32x4){0.f, 0.f, 0.f, 0.f};
#pragma unroll
        for (int kk = 0; kk < 4; ++kk) {
            const bf16x8 b = *reinterpret_cast<const bf16x8*>(
                Bt + (size_t)(ct * 16 + lrow) * 128 + kk * 32 + lk8);
            acc[ct] = __builtin_amdgcn_mfma_f32_16x16x32_bf16(a[kk], b, acc[ct], 0, 0, 0);
        }
    }

#pragma unroll
    for (int ct = 0; ct < 8; ++ct) {
        const int ch = ct * 16 + lrow;
        const float bv = bias[ch];
#pragma unroll
        for (int r = 0; r < 4; ++r) {
            const int node = node0 + (lane >> 4) * 4 + r;
            out[(size_t)node * HID_CH + ch] = acc[ct][r] + bv;
        }
    }
}

// ---------------- fallback (old atomic path) ----------------

__global__ __launch_bounds__(256) void sage_scatter(
    const int* __restrict__ ei, const float* __restrict__ h,
    float* __restrict__ agg, float* __restrict__ deg)
{
    const int gtid = blockIdx.x * blockDim.x + threadIdx.x;
    const int edge = gtid >> 6;
    const int lane = threadIdx.x & 63;
    if (edge >= N_EDGES) return;
    const int dst = ei[edge];
    const int src = ei[N_EDGES + edge];
    atomicAdd(&agg[(size_t)dst * IN_CH + lane], h[(size_t)src * IN_CH + lane]);
    if (lane == 0) atomicAdd(&deg[dst], 1.0f);
}

__global__ __launch_bounds__(128) void sage_node(
    const float* __restrict__ h, const float* __restrict__ agg,
    const float* __restrict__ deg, const float* __restrict__ Wl,
    const float* __restrict__ bias, const float* __restrict__ Wr,
    float* __restrict__ out)
{
    const int t = threadIdx.x;
    float wl[IN_CH], wr[IN_CH];
#pragma unroll
    for (int k = 0; k < IN_CH; ++k) {
        wl[k] = Wl[k * HID_CH + t];
        wr[k] = Wr[k * HID_CH + t];
    }
    const float b = bias[t];
    __shared__ float s_mean[IN_CH];
    __shared__ float s_h[IN_CH];
    for (int n = blockIdx.x; n < N_NODES; n += gridDim.x) {
        __syncthreads();
        if (t < IN_CH) {
            const float inv = 1.0f / fmaxf(deg[n], 1.0f);
            s_mean[t] = agg[(size_t)n * IN_CH + t] * inv;
            s_h[t] = h[(size_t)n * IN_CH + t];
        }
        __syncthreads();
        float acc = b;
#pragma unroll
        for (int k = 0; k < IN_CH; ++k) {
            acc = fmaf(s_mean[k], wl[k], acc);
            acc = fmaf(s_h[k], wr[k], acc);
        }
        out[(size_t)n * HID_CH + t] = acc;
    }
}

extern "C" void kernel_launch(void* const* d_in, const int* in_sizes, int n_in,
                              void* d_out, int out_size, void* d_ws, size_t ws_size,
                              hipStream_t stream) {
    // inputs: 0=x (unused), 1=edge_index, 2=emb_weight, 3=lin_l_w, 4=lin_l_b, 5=lin_r_w
    const int* ei = (const int*)d_in[1];
    const float* h = (const float*)d_in[2];
    const float* Wl = (const float*)d_in[3];
    const float* b = (const float*)d_in[4];
    const float* Wr = (const float*)d_in[5];
    float* out = (float*)d_out;

    // ws layout (4B elements):
    //   node_cnt   [0,       100000)
    //   node_start [100000,  200000)
    //   bin_tot    [200000,  200391)   (zeroed)
    //   bin_cursor [200391,  200782)   (zeroed)
    //   parts      [200800,  201191)
    //   Bt         [201200,  209392)   (bf16 128x128 = 8192 dwords)
    //   bucket     [400000, 2000000)   (1.6M dwords)
    //   meanb      [2000000, 5200000)  (bf16 100000x64 = 3.2M dwords)
    //   stage      [5200000, 6800000)  (packed int x 1.6M) -- consumed by bucket2,
    //   hb         [5200000, 8400000)  then overwritten by cvt_h (same region)
    const size_t need = 8400000ull * 4ull;

    if (ws_size >= need) {
        int* wsi = (int*)d_ws;
        int* node_cnt = wsi;
        int* node_start = wsi + 100000;
        int* bin_tot = wsi + 200000;
        int* bin_cursor = wsi + 200391;
        int* parts = wsi + 200800;
        unsigned short* Bt = (unsigned short*)(wsi + 201200);
        int* bucket = wsi + 400000;
        unsigned short* meanb = (unsigned short*)(wsi + 2000000);
        int* stage = wsi + 5200000;
        unsigned short* hb = (unsigned short*)(wsi + 5200000);

        hipMemsetAsync(bin_tot, 0, (200782 - 200000) * sizeof(int), stream);

        sage_prep<<<HIST_BLOCKS + CVTW_BLOCKS, 256, 0, stream>>>(ei, Wl, Wr, bin_tot, Bt);
        sage_stage<<<HIST_BLOCKS, 256, 0, stream>>>(ei, bin_tot, parts, bin_cursor, stage);
        sage_bucket2<<<NBINS, 256, 0, stream>>>(stage, parts, node_cnt, node_start, bucket);
        sage_cvt_h<<<1024, 256, 0, stream>>>(h, hb);  // overwrites stage (safe: bucket2 done)
        sage_gather_mean<<<(N_NODES + 3) / 4, 256, 0, stream>>>(node_cnt, node_start, bucket, hb, meanb);
        sage_mfma<<<(N_NODES / 16 + 3) / 4, 256, 0, stream>>>(meanb, hb, Bt, b, out);
    } else {
        // fallback: atomic scatter path
        float* agg = (float*)d_ws;
        float* deg = agg + (size_t)N_NODES * IN_CH;
        hipMemsetAsync(d_ws, 0, ((size_t)N_NODES * IN_CH + N_NODES) * sizeof(float), stream);
        sage_scatter<<<(int)(((long long)N_EDGES * 64 + 255) / 256), 256, 0, stream>>>(ei, h, agg, deg);
        sage_node<<<4096, 128, 0, stream>>>(h, agg, deg, Wl, b, Wr, out);
    }
}

// Round 12
// 161.080 us; speedup vs baseline: 3.1811x; 1.0470x over previous
//
#include <hip/hip_runtime.h>

#define N_NODES 100000
#define N_EDGES 1600000
#define IN_CH 64
#define HID_CH 128

#define BIN_SZ 256                                     // nodes per bin
#define BIN_BITS 8
#define NBINS ((N_NODES + BIN_SZ - 1) / BIN_SZ)        // 391 bins
#define EPB 2048                                       // edges per stage block
#define HIST_BLOCKS ((N_EDGES + EPB - 1) / EPB)        // 782
#define CVTH_BLOCKS 1024
#define CVTW_BLOCKS ((HID_CH * HID_CH + 255) / 256)    // 64
#define BIN_CACHE 8192                                 // LDS edge cache per bin

typedef __attribute__((ext_vector_type(8))) short bf16x8;  // 8 bf16 = 4 VGPR
typedef __attribute__((ext_vector_type(4))) float f32x4;

static __device__ __forceinline__ unsigned short f2bf(float f) {
    union { float f; unsigned int u; } v; v.f = f;
    const unsigned int u = v.u;
    return (unsigned short)((u + 0x7FFFu + ((u >> 16) & 1u)) >> 16);  // RNE
}

// ---------------- prep: bin hist + h->bf16 + weight pack (fused) ----------

__global__ __launch_bounds__(256) void sage_prep(
    const int* __restrict__ ei, const float* __restrict__ h,
    const float* __restrict__ Wl, const float* __restrict__ Wr,
    int* __restrict__ bin_tot, unsigned short* __restrict__ hb,
    unsigned short* __restrict__ Bt)
{
    const int t = threadIdx.x;
    const int bid = blockIdx.x;
    if (bid < HIST_BLOCKS) {
        __shared__ int s_bins[NBINS];
        for (int i = t; i < NBINS; i += 256) s_bins[i] = 0;
        __syncthreads();
        const int e0 = bid * EPB;
#pragma unroll
        for (int k = 0; k < 8; ++k) {
            const int e = e0 + k * 256 + t;
            if (e < N_EDGES) atomicAdd(&s_bins[ei[e] >> BIN_BITS], 1);
        }
        __syncthreads();
        for (int i = t; i < NBINS; i += 256) {
            const int c = s_bins[i];
            if (c > 0) atomicAdd(&bin_tot[i], c);
        }
    } else if (bid < HIST_BLOCKS + CVTH_BLOCKS) {
        const int n4 = N_NODES * IN_CH / 4;
        for (int i = (bid - HIST_BLOCKS) * 256 + t; i < n4;
             i += CVTH_BLOCKS * 256) {
            const float4 v = reinterpret_cast<const float4*>(h)[i];
            ushort4 o;
            o.x = f2bf(v.x); o.y = f2bf(v.y); o.z = f2bf(v.z); o.w = f2bf(v.w);
            reinterpret_cast<ushort4*>(hb)[i] = o;
        }
    } else {
        // Bt[n][k] = bf16( k<64 ? Wl[k][n] : Wr[k-64][n] )
        const int i = (bid - HIST_BLOCKS - CVTH_BLOCKS) * 256 + t;
        if (i < HID_CH * HID_CH) {
            const int n = i >> 7, k = i & 127;
            const float v = (k < 64) ? Wl[k * HID_CH + n] : Wr[(k - 64) * HID_CH + n];
            Bt[i] = f2bf(v);
        }
    }
}

// ---------------- exclusive scan of 391 bin totals (single block) --------

__global__ __launch_bounds__(256) void sage_scan(
    const int* __restrict__ bin_tot, int* __restrict__ parts)
{
    __shared__ int sc[512];
    const int t = threadIdx.x;
    sc[t] = (t < NBINS) ? bin_tot[t] : 0;
    sc[t + 256] = (t + 256 < NBINS) ? bin_tot[t + 256] : 0;
    __syncthreads();
    for (int off = 1; off < 512; off <<= 1) {
        const int a = (t >= off) ? sc[t - off] : 0;
        const int b = (t + 256 >= off) ? sc[t + 256 - off] : 0;
        __syncthreads();
        sc[t] += a; sc[t + 256] += b;
        __syncthreads();
    }
    for (int i = t; i < NBINS; i += 256)
        parts[i] = (i > 0) ? sc[i - 1] : 0;
}

// ---------------- stage: partition edges into 391 bin regions -------------
// Packed record: ((dst & 255) << 17) | src   (src < 2^17).
__global__ __launch_bounds__(256) void sage_stage(
    const int* __restrict__ ei, const int* __restrict__ parts,
    int* __restrict__ bin_cursor, int* __restrict__ stage)
{
    __shared__ int s_cnt[NBINS];
    __shared__ int s_base[NBINS];
    const int t = threadIdx.x;
    for (int i = t; i < NBINS; i += 256) s_cnt[i] = 0;
    __syncthreads();
    const int e0 = blockIdx.x * EPB;
    int pk[8], bin[8];
#pragma unroll
    for (int k = 0; k < 8; ++k) {
        const int e = e0 + k * 256 + t;
        if (e < N_EDGES) {
            const int dst = ei[e];
            const int src = ei[N_EDGES + e];
            bin[k] = dst >> BIN_BITS;
            pk[k] = ((dst & (BIN_SZ - 1)) << 17) | src;
            atomicAdd(&s_cnt[bin[k]], 1);
        } else bin[k] = -1;
    }
    __syncthreads();
    for (int i = t; i < NBINS; i += 256) {
        const int c = s_cnt[i];
        s_base[i] = (c > 0) ? (parts[i] + atomicAdd(&bin_cursor[i], c)) : 0;
        s_cnt[i] = 0;
    }
    __syncthreads();
#pragma unroll
    for (int k = 0; k < 8; ++k) {
        if (bin[k] >= 0) {
            const int p = s_base[bin[k]] + atomicAdd(&s_cnt[bin[k]], 1);
            stage[p] = pk[k];
        }
    }
}

// ---------------- bucket2: per-bin CSR finalize ---------------------------

__global__ __launch_bounds__(256) void sage_bucket2(
    const int* __restrict__ stage, const int* __restrict__ parts,
    int* __restrict__ node_cnt, int* __restrict__ node_start,
    int* __restrict__ bucket)
{
    __shared__ int s_cnt[BIN_SZ];
    __shared__ int s_off[BIN_SZ];
    __shared__ int s_cur[BIN_SZ];
    __shared__ int s_edges[BIN_CACHE];
    const int b = blockIdx.x;
    const int t = threadIdx.x;
    s_cnt[t] = 0; s_cur[t] = 0;
    __syncthreads();
    const int start = parts[b];
    const int end = (b + 1 < NBINS) ? parts[b + 1] : N_EDGES;
    const int len = end - start;
    const bool cached = (len <= BIN_CACHE);
    if (cached) {
        for (int i = t; i < len; i += 256) {
            const int p = stage[start + i];
            s_edges[i] = p;
            atomicAdd(&s_cnt[p >> 17], 1);
        }
    } else {
        for (int i = t; i < len; i += 256)
            atomicAdd(&s_cnt[stage[start + i] >> 17], 1);
    }
    __syncthreads();
    const int v = s_cnt[t];
    s_off[t] = v;
    __syncthreads();
    for (int off = 1; off < 256; off <<= 1) {
        const int a = (t >= off) ? s_off[t - off] : 0;
        __syncthreads();
        s_off[t] += a;
        __syncthreads();
    }
    const int excl = s_off[t] - v;
    s_off[t] = excl;
    __syncthreads();
    const int node = (b << BIN_BITS) + t;
    if (node < N_NODES) {
        node_cnt[node] = v;
        node_start[node] = start + excl;
    }
    if (cached) {
        for (int i = t; i < len; i += 256) {
            const int p = s_edges[i];
            const int l = p >> 17;
            bucket[start + s_off[l] + atomicAdd(&s_cur[l], 1)] = p & 0x1FFFF;
        }
    } else {
        for (int i = t; i < len; i += 256) {
            const int p = stage[start + i];
            const int l = p >> 17;
            bucket[start + s_off[l] + atomicAdd(&s_cur[l], 1)] = p & 0x1FFFF;
        }
    }
}

// ---------------- fused gather+mean+MFMA ----------------------------------
// One block = 16 nodes = one m-tile. Phase 1: 4 waves gather 4 nodes each
// (8 edge slots x 8 lanes x 16B per row), write bf16 mean rows to LDS
// (row stride 144B -> 2-way bank alias only, free). Phase 2: each wave
// computes 2 col-tiles (4 MFMA each) and writes out directly.
__global__ __launch_bounds__(256) void sage_gmfma(
    const int* __restrict__ node_cnt, const int* __restrict__ node_start,
    const int* __restrict__ bucket, const unsigned short* __restrict__ hb,
    const unsigned short* __restrict__ Bt, const float* __restrict__ bias,
    float* __restrict__ out)
{
    __shared__ unsigned short s_mean[16][72];  // padded: 144B row stride
    const int t = threadIdx.x;
    const int w = t >> 6;           // wave 0..3
    const int lane = t & 63;
    const int sub = lane >> 3;      // edge slot 0..7
    const int c8 = lane & 7;        // 8-channel group within row
    const int node0 = blockIdx.x * 16;

    // ---- phase 1: gather means for 4 nodes per wave ----
    for (int nn = 0; nn < 4; ++nn) {
        const int node = node0 + w * 4 + nn;
        const int d = node_cnt[node];
        const int start = node_start[node];

        float acc[8] = {0.f, 0.f, 0.f, 0.f, 0.f, 0.f, 0.f, 0.f};
        int i = 0;
        for (; i + 8 <= d; i += 8) {
            const int s = bucket[start + i + sub];
            const uint4 v = *reinterpret_cast<const uint4*>(hb + (size_t)s * IN_CH + c8 * 8);
            union { unsigned int u; float f; } lo, hi;
#pragma unroll
            for (int j = 0; j < 4; ++j) {
                const unsigned int ww = (&v.x)[j];
                lo.u = ww << 16;         acc[2 * j] += lo.f;
                hi.u = ww & 0xFFFF0000u; acc[2 * j + 1] += hi.f;
            }
        }
        if (i + sub < d) {
            const int s = bucket[start + i + sub];
            const uint4 v = *reinterpret_cast<const uint4*>(hb + (size_t)s * IN_CH + c8 * 8);
            union { unsigned int u; float f; } lo, hi;
#pragma unroll
            for (int j = 0; j < 4; ++j) {
                const unsigned int ww = (&v.x)[j];
                lo.u = ww << 16;         acc[2 * j] += lo.f;
                hi.u = ww & 0xFFFF0000u; acc[2 * j + 1] += hi.f;
            }
        }
#pragma unroll
        for (int j = 0; j < 8; ++j) {
            acc[j] += __shfl_xor(acc[j], 8);
            acc[j] += __shfl_xor(acc[j], 16);
            acc[j] += __shfl_xor(acc[j], 32);
        }
        if (sub == 0) {
            const float inv = 1.0f / (float)((d > 1) ? d : 1);
            uint4 o;
#pragma unroll
            for (int j = 0; j < 4; ++j) {
                const unsigned int l = f2bf(acc[2 * j] * inv);
                const unsigned int hh = f2bf(acc[2 * j + 1] * inv);
                (&o.x)[j] = l | (hh << 16);
            }
            *reinterpret_cast<uint4*>(&s_mean[w * 4 + nn][c8 * 8]) = o;
        }
    }
    __syncthreads();

    // ---- phase 2: MFMA; wave w handles col-tiles 2w, 2w+1 ----
    const int lrow = lane & 15;
    const int lk8 = (lane >> 4) * 8;

    bf16x8 a[4];
    a[0] = *reinterpret_cast<const bf16x8*>(&s_mean[lrow][lk8]);
    a[1] = *reinterpret_cast<const bf16x8*>(&s_mean[lrow][32 + lk8]);
    {
        const unsigned short* ah = hb + (size_t)(node0 + lrow) * IN_CH;
        a[2] = *reinterpret_cast<const bf16x8*>(ah + lk8);
        a[3] = *reinterpret_cast<const bf16x8*>(ah + 32 + lk8);
    }

#pragma unroll
    for (int c = 0; c < 2; ++c) {
        const int ct = 2 * w + c;
        f32x4 acc2 = (f32x4){0.f, 0.f, 0.f, 0.f};
#pragma unroll
        for (int kk = 0; kk < 4; ++kk) {
            const bf16x8 b = *reinterpret_cast<const bf16x8*>(
                Bt + (size_t)(ct * 16 + lrow) * 128 + kk * 32 + lk8);
            acc2 = __builtin_amdgcn_mfma_f32_16x16x32_bf16(a[kk], b, acc2, 0, 0, 0);
        }
        const int ch = ct * 16 + lrow;
        const float bv = bias[ch];
#pragma unroll
        for (int r = 0; r < 4; ++r) {
            const int node = node0 + (lane >> 4) * 4 + r;
            out[(size_t)node * HID_CH + ch] = acc2[r] + bv;
        }
    }
}

// ---------------- fallback (old atomic path) ----------------

__global__ __launch_bounds__(256) void sage_scatter(
    const int* __restrict__ ei, const float* __restrict__ h,
    float* __restrict__ agg, float* __restrict__ deg)
{
    const int gtid = blockIdx.x * blockDim.x + threadIdx.x;
    const int edge = gtid >> 6;
    const int lane = threadIdx.x & 63;
    if (edge >= N_EDGES) return;
    const int dst = ei[edge];
    const int src = ei[N_EDGES + edge];
    atomicAdd(&agg[(size_t)dst * IN_CH + lane], h[(size_t)src * IN_CH + lane]);
    if (lane == 0) atomicAdd(&deg[dst], 1.0f);
}

__global__ __launch_bounds__(128) void sage_node(
    const float* __restrict__ h, const float* __restrict__ agg,
    const float* __restrict__ deg, const float* __restrict__ Wl,
    const float* __restrict__ bias, const float* __restrict__ Wr,
    float* __restrict__ out)
{
    const int t = threadIdx.x;
    float wl[IN_CH], wr[IN_CH];
#pragma unroll
    for (int k = 0; k < IN_CH; ++k) {
        wl[k] = Wl[k * HID_CH + t];
        wr[k] = Wr[k * HID_CH + t];
    }
    const float b = bias[t];
    __shared__ float s_mean[IN_CH];
    __shared__ float s_h[IN_CH];
    for (int n = blockIdx.x; n < N_NODES; n += gridDim.x) {
        __syncthreads();
        if (t < IN_CH) {
            const float inv = 1.0f / fmaxf(deg[n], 1.0f);
            s_mean[t] = agg[(size_t)n * IN_CH + t] * inv;
            s_h[t] = h[(size_t)n * IN_CH + t];
        }
        __syncthreads();
        float acc = b;
#pragma unroll
        for (int k = 0; k < IN_CH; ++k) {
            acc = fmaf(s_mean[k], wl[k], acc);
            acc = fmaf(s_h[k], wr[k], acc);
        }
        out[(size_t)n * HID_CH + t] = acc;
    }
}

extern "C" void kernel_launch(void* const* d_in, const int* in_sizes, int n_in,
                              void* d_out, int out_size, void* d_ws, size_t ws_size,
                              hipStream_t stream) {
    // inputs: 0=x (unused), 1=edge_index, 2=emb_weight, 3=lin_l_w, 4=lin_l_b, 5=lin_r_w
    const int* ei = (const int*)d_in[1];
    const float* h = (const float*)d_in[2];
    const float* Wl = (const float*)d_in[3];
    const float* b = (const float*)d_in[4];
    const float* Wr = (const float*)d_in[5];
    float* out = (float*)d_out;

    // ws layout (4B elements):
    //   node_cnt   [0,       100000)
    //   node_start [100000,  200000)
    //   bin_tot    [200000,  200391)   (zeroed)
    //   bin_cursor [200391,  200782)   (zeroed)
    //   parts      [200800,  201191)
    //   Bt         [201200,  209392)   (bf16 128x128 = 8192 dwords)
    //   bucket     [400000, 2000000)   (1.6M dwords)
    //   hb         [2000000, 5200000)  (bf16 100000x64 = 3.2M dwords)
    //   stage      [5200000, 6800000)  (packed int x 1.6M)
    const size_t need = 6800000ull * 4ull;

    if (ws_size >= need) {
        int* wsi = (int*)d_ws;
        int* node_cnt = wsi;
        int* node_start = wsi + 100000;
        int* bin_tot = wsi + 200000;
        int* bin_cursor = wsi + 200391;
        int* parts = wsi + 200800;
        unsigned short* Bt = (unsigned short*)(wsi + 201200);
        int* bucket = wsi + 400000;
        unsigned short* hb = (unsigned short*)(wsi + 2000000);
        int* stage = wsi + 5200000;

        hipMemsetAsync(bin_tot, 0, (200782 - 200000) * sizeof(int), stream);

        sage_prep<<<HIST_BLOCKS + CVTH_BLOCKS + CVTW_BLOCKS, 256, 0, stream>>>(
            ei, h, Wl, Wr, bin_tot, hb, Bt);
        sage_scan<<<1, 256, 0, stream>>>(bin_tot, parts);
        sage_stage<<<HIST_BLOCKS, 256, 0, stream>>>(ei, parts, bin_cursor, stage);
        sage_bucket2<<<NBINS, 256, 0, stream>>>(stage, parts, node_cnt, node_start, bucket);
        sage_gmfma<<<N_NODES / 16, 256, 0, stream>>>(node_cnt, node_start, bucket, hb, Bt, b, out);
    } else {
        // fallback: atomic scatter path
        float* agg = (float*)d_ws;
        float* deg = agg + (size_t)N_NODES * IN_CH;
        hipMemsetAsync(d_ws, 0, ((size_t)N_NODES * IN_CH + N_NODES) * sizeof(float), stream);
        sage_scatter<<<(int)(((long long)N_EDGES * 64 + 255) / 256), 256, 0, stream>>>(ei, h, agg, deg);
        sage_node<<<4096, 128, 0, stream>>>(h, agg, deg, Wl, b, Wr, out);
    }
}

// Round 13
// 160.184 us; speedup vs baseline: 3.1989x; 1.0056x over previous
//
#include <hip/hip_runtime.h>

#define N_NODES 100000
#define N_EDGES 1600000
#define IN_CH 64
#define HID_CH 128

#define BIN_SZ 256                                     // nodes per bin
#define BIN_BITS 8
#define NBINS ((N_NODES + BIN_SZ - 1) / BIN_SZ)        // 391 bins
#define EPB 2048                                       // edges per stage block
#define HIST_BLOCKS ((N_EDGES + EPB - 1) / EPB)        // 782
#define CVTH_BLOCKS 1024
#define CVTW_BLOCKS ((HID_CH * HID_CH + 255) / 256)    // 64
#define BIN_CACHE 8192                                 // LDS edge cache per bin

typedef __attribute__((ext_vector_type(8))) short bf16x8;  // 8 bf16 = 4 VGPR
typedef __attribute__((ext_vector_type(4))) float f32x4;

static __device__ __forceinline__ unsigned short f2bf(float f) {
    union { float f; unsigned int u; } v; v.f = f;
    const unsigned int u = v.u;
    return (unsigned short)((u + 0x7FFFu + ((u >> 16) & 1u)) >> 16);  // RNE
}

#define UNPACK_ADD(A, V) do {                                         \
    union { unsigned int u; float f; } lo_, hi_;                      \
    _Pragma("unroll")                                                 \
    for (int j_ = 0; j_ < 4; ++j_) {                                  \
        const unsigned int w_ = (&(V).x)[j_];                         \
        lo_.u = w_ << 16;         A[2 * j_] += lo_.f;                 \
        hi_.u = w_ & 0xFFFF0000u; A[2 * j_ + 1] += hi_.f;             \
    } } while (0)

// ---------------- prep: bin hist + h->bf16 + weight pack (fused) ----------

__global__ __launch_bounds__(256) void sage_prep(
    const int* __restrict__ ei, const float* __restrict__ h,
    const float* __restrict__ Wl, const float* __restrict__ Wr,
    int* __restrict__ bin_tot, unsigned short* __restrict__ hb,
    unsigned short* __restrict__ Bt)
{
    const int t = threadIdx.x;
    const int bid = blockIdx.x;
    if (bid < HIST_BLOCKS) {
        __shared__ int s_bins[NBINS];
        for (int i = t; i < NBINS; i += 256) s_bins[i] = 0;
        __syncthreads();
        const int e0 = bid * EPB;
#pragma unroll
        for (int k = 0; k < 8; ++k) {
            const int e = e0 + k * 256 + t;
            if (e < N_EDGES) atomicAdd(&s_bins[ei[e] >> BIN_BITS], 1);
        }
        __syncthreads();
        for (int i = t; i < NBINS; i += 256) {
            const int c = s_bins[i];
            if (c > 0) atomicAdd(&bin_tot[i], c);
        }
    } else if (bid < HIST_BLOCKS + CVTH_BLOCKS) {
        const int n4 = N_NODES * IN_CH / 4;
        for (int i = (bid - HIST_BLOCKS) * 256 + t; i < n4;
             i += CVTH_BLOCKS * 256) {
            const float4 v = reinterpret_cast<const float4*>(h)[i];
            ushort4 o;
            o.x = f2bf(v.x); o.y = f2bf(v.y); o.z = f2bf(v.z); o.w = f2bf(v.w);
            reinterpret_cast<ushort4*>(hb)[i] = o;
        }
    } else {
        // Bt[n][k] = bf16( k<64 ? Wl[k][n] : Wr[k-64][n] )
        const int i = (bid - HIST_BLOCKS - CVTH_BLOCKS) * 256 + t;
        if (i < HID_CH * HID_CH) {
            const int n = i >> 7, k = i & 127;
            const float v = (k < 64) ? Wl[k * HID_CH + n] : Wr[(k - 64) * HID_CH + n];
            Bt[i] = f2bf(v);
        }
    }
}

// ---------------- exclusive scan of 391 bin totals (single block) --------

__global__ __launch_bounds__(256) void sage_scan(
    const int* __restrict__ bin_tot, int* __restrict__ parts)
{
    __shared__ int sc[512];
    const int t = threadIdx.x;
    sc[t] = (t < NBINS) ? bin_tot[t] : 0;
    sc[t + 256] = (t + 256 < NBINS) ? bin_tot[t + 256] : 0;
    __syncthreads();
    for (int off = 1; off < 512; off <<= 1) {
        const int a = (t >= off) ? sc[t - off] : 0;
        const int b = (t + 256 >= off) ? sc[t + 256 - off] : 0;
        __syncthreads();
        sc[t] += a; sc[t + 256] += b;
        __syncthreads();
    }
    for (int i = t; i < NBINS; i += 256)
        parts[i] = (i > 0) ? sc[i - 1] : 0;
}

// ---------------- stage: partition edges into 391 bin regions -------------
// Packed record: ((dst & 255) << 17) | src   (src < 2^17).
__global__ __launch_bounds__(256) void sage_stage(
    const int* __restrict__ ei, const int* __restrict__ parts,
    int* __restrict__ bin_cursor, int* __restrict__ stage)
{
    __shared__ int s_cnt[NBINS];
    __shared__ int s_base[NBINS];
    const int t = threadIdx.x;
    for (int i = t; i < NBINS; i += 256) s_cnt[i] = 0;
    __syncthreads();
    const int e0 = blockIdx.x * EPB;
    int pk[8], bin[8];
#pragma unroll
    for (int k = 0; k < 8; ++k) {
        const int e = e0 + k * 256 + t;
        if (e < N_EDGES) {
            const int dst = ei[e];
            const int src = ei[N_EDGES + e];
            bin[k] = dst >> BIN_BITS;
            pk[k] = ((dst & (BIN_SZ - 1)) << 17) | src;
            atomicAdd(&s_cnt[bin[k]], 1);
        } else bin[k] = -1;
    }
    __syncthreads();
    for (int i = t; i < NBINS; i += 256) {
        const int c = s_cnt[i];
        s_base[i] = (c > 0) ? (parts[i] + atomicAdd(&bin_cursor[i], c)) : 0;
        s_cnt[i] = 0;
    }
    __syncthreads();
#pragma unroll
    for (int k = 0; k < 8; ++k) {
        if (bin[k] >= 0) {
            const int p = s_base[bin[k]] + atomicAdd(&s_cnt[bin[k]], 1);
            stage[p] = pk[k];
        }
    }
}

// ---------------- bucket2: per-bin CSR finalize ---------------------------

__global__ __launch_bounds__(256) void sage_bucket2(
    const int* __restrict__ stage, const int* __restrict__ parts,
    int* __restrict__ node_cnt, int* __restrict__ node_start,
    int* __restrict__ bucket)
{
    __shared__ int s_cnt[BIN_SZ];
    __shared__ int s_off[BIN_SZ];
    __shared__ int s_cur[BIN_SZ];
    __shared__ int s_edges[BIN_CACHE];
    const int b = blockIdx.x;
    const int t = threadIdx.x;
    s_cnt[t] = 0; s_cur[t] = 0;
    __syncthreads();
    const int start = parts[b];
    const int end = (b + 1 < NBINS) ? parts[b + 1] : N_EDGES;
    const int len = end - start;
    const bool cached = (len <= BIN_CACHE);
    if (cached) {
        for (int i = t; i < len; i += 256) {
            const int p = stage[start + i];
            s_edges[i] = p;
            atomicAdd(&s_cnt[p >> 17], 1);
        }
    } else {
        for (int i = t; i < len; i += 256)
            atomicAdd(&s_cnt[stage[start + i] >> 17], 1);
    }
    __syncthreads();
    const int v = s_cnt[t];
    s_off[t] = v;
    __syncthreads();
    for (int off = 1; off < 256; off <<= 1) {
        const int a = (t >= off) ? s_off[t - off] : 0;
        __syncthreads();
        s_off[t] += a;
        __syncthreads();
    }
    const int excl = s_off[t] - v;
    s_off[t] = excl;
    __syncthreads();
    const int node = (b << BIN_BITS) + t;
    if (node < N_NODES) {
        node_cnt[node] = v;
        node_start[node] = start + excl;
    }
    if (cached) {
        for (int i = t; i < len; i += 256) {
            const int p = s_edges[i];
            const int l = p >> 17;
            bucket[start + s_off[l] + atomicAdd(&s_cur[l], 1)] = p & 0x1FFFF;
        }
    } else {
        for (int i = t; i < len; i += 256) {
            const int p = stage[start + i];
            const int l = p >> 17;
            bucket[start + s_off[l] + atomicAdd(&s_cur[l], 1)] = p & 0x1FFFF;
        }
    }
}

// ---------------- fused gather+mean+MFMA ----------------------------------
// One block = 16 nodes = one m-tile. Phase 1: each wave gathers its 4 nodes
// INTERLEAVED (4 independent idx->row chains in flight) -> bf16 means to LDS.
// Phase 2: each wave computes 2 col-tiles (4 MFMA) and writes out directly.
__global__ __launch_bounds__(256) void sage_gmfma(
    const int* __restrict__ node_cnt, const int* __restrict__ node_start,
    const int* __restrict__ bucket, const unsigned short* __restrict__ hb,
    const unsigned short* __restrict__ Bt, const float* __restrict__ bias,
    float* __restrict__ out)
{
    __shared__ unsigned short s_mean[16][72];  // padded: 144B row stride
    const int t = threadIdx.x;
    const int w = t >> 6;           // wave 0..3
    const int lane = t & 63;
    const int sub = lane >> 3;      // edge slot 0..7
    const int c8 = lane & 7;        // 8-channel group within row
    const int node0 = blockIdx.x * 16;

    // ---- phase 1: interleaved gather for the wave's 4 nodes ----
    int d_[4], st_[4];
#pragma unroll
    for (int nn = 0; nn < 4; ++nn) {
        const int node = node0 + w * 4 + nn;
        d_[nn] = node_cnt[node];
        st_[nn] = node_start[node];
    }
    int maxd = d_[0];
#pragma unroll
    for (int nn = 1; nn < 4; ++nn) maxd = (d_[nn] > maxd) ? d_[nn] : maxd;

    float a0[8] = {0.f,0.f,0.f,0.f,0.f,0.f,0.f,0.f};
    float a1[8] = {0.f,0.f,0.f,0.f,0.f,0.f,0.f,0.f};
    float a2[8] = {0.f,0.f,0.f,0.f,0.f,0.f,0.f,0.f};
    float a3[8] = {0.f,0.f,0.f,0.f,0.f,0.f,0.f,0.f};

    for (int g = 0; g < maxd; g += 8) {
        const int e = g + sub;
        // issue all 4 index loads first (independent), then the 4 row loads
        int s0 = -1, s1 = -1, s2 = -1, s3 = -1;
        if (e < d_[0]) s0 = bucket[st_[0] + e];
        if (e < d_[1]) s1 = bucket[st_[1] + e];
        if (e < d_[2]) s2 = bucket[st_[2] + e];
        if (e < d_[3]) s3 = bucket[st_[3] + e];
        if (s0 >= 0) {
            const uint4 v = *reinterpret_cast<const uint4*>(hb + (size_t)s0 * IN_CH + c8 * 8);
            UNPACK_ADD(a0, v);
        }
        if (s1 >= 0) {
            const uint4 v = *reinterpret_cast<const uint4*>(hb + (size_t)s1 * IN_CH + c8 * 8);
            UNPACK_ADD(a1, v);
        }
        if (s2 >= 0) {
            const uint4 v = *reinterpret_cast<const uint4*>(hb + (size_t)s2 * IN_CH + c8 * 8);
            UNPACK_ADD(a2, v);
        }
        if (s3 >= 0) {
            const uint4 v = *reinterpret_cast<const uint4*>(hb + (size_t)s3 * IN_CH + c8 * 8);
            UNPACK_ADD(a3, v);
        }
    }

#define REDUCE_STORE(A, NN) do {                                        \
    _Pragma("unroll")                                                   \
    for (int j = 0; j < 8; ++j) {                                       \
        A[j] += __shfl_xor(A[j], 8);                                    \
        A[j] += __shfl_xor(A[j], 16);                                   \
        A[j] += __shfl_xor(A[j], 32);                                   \
    }                                                                   \
    if (sub == 0) {                                                     \
        const float inv = 1.0f / (float)((d_[NN] > 1) ? d_[NN] : 1);    \
        uint4 o;                                                        \
        _Pragma("unroll")                                               \
        for (int j = 0; j < 4; ++j) {                                   \
            const unsigned int l = f2bf(A[2 * j] * inv);                \
            const unsigned int hh = f2bf(A[2 * j + 1] * inv);           \
            (&o.x)[j] = l | (hh << 16);                                 \
        }                                                               \
        *reinterpret_cast<uint4*>(&s_mean[w * 4 + NN][c8 * 8]) = o;     \
    } } while (0)

    REDUCE_STORE(a0, 0);
    REDUCE_STORE(a1, 1);
    REDUCE_STORE(a2, 2);
    REDUCE_STORE(a3, 3);
#undef REDUCE_STORE

    __syncthreads();

    // ---- phase 2: MFMA; wave w handles col-tiles 2w, 2w+1 ----
    const int lrow = lane & 15;
    const int lk8 = (lane >> 4) * 8;

    bf16x8 a[4];
    a[0] = *reinterpret_cast<const bf16x8*>(&s_mean[lrow][lk8]);
    a[1] = *reinterpret_cast<const bf16x8*>(&s_mean[lrow][32 + lk8]);
    {
        const unsigned short* ah = hb + (size_t)(node0 + lrow) * IN_CH;
        a[2] = *reinterpret_cast<const bf16x8*>(ah + lk8);
        a[3] = *reinterpret_cast<const bf16x8*>(ah + 32 + lk8);
    }

#pragma unroll
    for (int c = 0; c < 2; ++c) {
        const int ct = 2 * w + c;
        f32x4 acc2 = (f32x4){0.f, 0.f, 0.f, 0.f};
#pragma unroll
        for (int kk = 0; kk < 4; ++kk) {
            const bf16x8 b = *reinterpret_cast<const bf16x8*>(
                Bt + (size_t)(ct * 16 + lrow) * 128 + kk * 32 + lk8);
            acc2 = __builtin_amdgcn_mfma_f32_16x16x32_bf16(a[kk], b, acc2, 0, 0, 0);
        }
        const int ch = ct * 16 + lrow;
        const float bv = bias[ch];
#pragma unroll
        for (int r = 0; r < 4; ++r) {
            const int node = node0 + (lane >> 4) * 4 + r;
            out[(size_t)node * HID_CH + ch] = acc2[r] + bv;
        }
    }
}

// ---------------- fallback (old atomic path) ----------------

__global__ __launch_bounds__(256) void sage_scatter(
    const int* __restrict__ ei, const float* __restrict__ h,
    float* __restrict__ agg, float* __restrict__ deg)
{
    const int gtid = blockIdx.x * blockDim.x + threadIdx.x;
    const int edge = gtid >> 6;
    const int lane = threadIdx.x & 63;
    if (edge >= N_EDGES) return;
    const int dst = ei[edge];
    const int src = ei[N_EDGES + edge];
    atomicAdd(&agg[(size_t)dst * IN_CH + lane], h[(size_t)src * IN_CH + lane]);
    if (lane == 0) atomicAdd(&deg[dst], 1.0f);
}

__global__ __launch_bounds__(128) void sage_node(
    const float* __restrict__ h, const float* __restrict__ agg,
    const float* __restrict__ deg, const float* __restrict__ Wl,
    const float* __restrict__ bias, const float* __restrict__ Wr,
    float* __restrict__ out)
{
    const int t = threadIdx.x;
    float wl[IN_CH], wr[IN_CH];
#pragma unroll
    for (int k = 0; k < IN_CH; ++k) {
        wl[k] = Wl[k * HID_CH + t];
        wr[k] = Wr[k * HID_CH + t];
    }
    const float b = bias[t];
    __shared__ float s_mean[IN_CH];
    __shared__ float s_h[IN_CH];
    for (int n = blockIdx.x; n < N_NODES; n += gridDim.x) {
        __syncthreads();
        if (t < IN_CH) {
            const float inv = 1.0f / fmaxf(deg[n], 1.0f);
            s_mean[t] = agg[(size_t)n * IN_CH + t] * inv;
            s_h[t] = h[(size_t)n * IN_CH + t];
        }
        __syncthreads();
        float acc = b;
#pragma unroll
        for (int k = 0; k < IN_CH; ++k) {
            acc = fmaf(s_mean[k], wl[k], acc);
            acc = fmaf(s_h[k], wr[k], acc);
        }
        out[(size_t)n * HID_CH + t] = acc;
    }
}

extern "C" void kernel_launch(void* const* d_in, const int* in_sizes, int n_in,
                              void* d_out, int out_size, void* d_ws, size_t ws_size,
                              hipStream_t stream) {
    // inputs: 0=x (unused), 1=edge_index, 2=emb_weight, 3=lin_l_w, 4=lin_l_b, 5=lin_r_w
    const int* ei = (const int*)d_in[1];
    const float* h = (const float*)d_in[2];
    const float* Wl = (const float*)d_in[3];
    const float* b = (const float*)d_in[4];
    const float* Wr = (const float*)d_in[5];
    float* out = (float*)d_out;

    // ws layout (4B elements):
    //   node_cnt   [0,       100000)
    //   node_start [100000,  200000)
    //   bin_tot    [200000,  200391)   (zeroed)
    //   bin_cursor [200391,  200782)   (zeroed)
    //   parts      [200800,  201191)
    //   Bt         [201200,  209392)   (bf16 128x128 = 8192 dwords)
    //   bucket     [400000, 2000000)   (1.6M dwords)
    //   hb         [2000000, 5200000)  (bf16 100000x64 = 3.2M dwords)
    //   stage      [5200000, 6800000)  (packed int x 1.6M)
    const size_t need = 6800000ull * 4ull;

    if (ws_size >= need) {
        int* wsi = (int*)d_ws;
        int* node_cnt = wsi;
        int* node_start = wsi + 100000;
        int* bin_tot = wsi + 200000;
        int* bin_cursor = wsi + 200391;
        int* parts = wsi + 200800;
        unsigned short* Bt = (unsigned short*)(wsi + 201200);
        int* bucket = wsi + 400000;
        unsigned short* hb = (unsigned short*)(wsi + 2000000);
        int* stage = wsi + 5200000;

        hipMemsetAsync(bin_tot, 0, (200782 - 200000) * sizeof(int), stream);

        sage_prep<<<HIST_BLOCKS + CVTH_BLOCKS + CVTW_BLOCKS, 256, 0, stream>>>(
            ei, h, Wl, Wr, bin_tot, hb, Bt);
        sage_scan<<<1, 256, 0, stream>>>(bin_tot, parts);
        sage_stage<<<HIST_BLOCKS, 256, 0, stream>>>(ei, parts, bin_cursor, stage);
        sage_bucket2<<<NBINS, 256, 0, stream>>>(stage, parts, node_cnt, node_start, bucket);
        sage_gmfma<<<N_NODES / 16, 256, 0, stream>>>(node_cnt, node_start, bucket, hb, Bt, b, out);
    } else {
        // fallback: atomic scatter path
        float* agg = (float*)d_ws;
        float* deg = agg + (size_t)N_NODES * IN_CH;
        hipMemsetAsync(d_ws, 0, ((size_t)N_NODES * IN_CH + N_NODES) * sizeof(float), stream);
        sage_scatter<<<(int)(((long long)N_EDGES * 64 + 255) / 256), 256, 0, stream>>>(ei, h, agg, deg);
        sage_node<<<4096, 128, 0, stream>>>(h, agg, deg, Wl, b, Wr, out);
    }
}